// Round 3
// baseline (4415.882 us; speedup 1.0000x reference)
//
#include <hip/hip_runtime.h>
#include <hip/hip_bf16.h>

// ---------------------------------------------------------------------------
// SemGCN forward, round 6.
//  * Fused res-stack redesigned to FIT the 128-VGPR tier (rounds 4/5 spilled
//    ~60 regs -> ~900MB scratch traffic; allocator pinned 128 regardless of
//    attributes):
//      - 8 batch rows/block, grid 1024 (4 blocks/CU, LDS ~36KB): residual
//        R = 32 VGPRs (was 64).
//      - phase-2 processes m-tiles in groups of 2: acc = 32 VGPRs (was 64).
//      - kk loop not unrolled: only 4 W-frags (16 regs) in flight (was 16).
//      - peak live ~120 < 128 -> no spills; occupancy 16 waves/CU (2x).
//  * gbar spin barrier (relaxed LLC atomics) kept from round 5 (passed).
//  * legacy per-layer path kept as runtime fallback (also catches the case
//    where cooperative residency validation fails).
// ---------------------------------------------------------------------------

#define BATCH 8192
#define NJ 16
#define FHID 128
#define NROWS (BATCH * NJ)   // 131072
#define NSLICE 32

typedef unsigned short u16;
typedef __attribute__((ext_vector_type(8))) short frag_ab;  // 8 bf16
typedef __attribute__((ext_vector_type(4))) short frag16;   // 4 bf16
typedef __attribute__((ext_vector_type(4))) float frag_cd;  // 4 fp32

__device__ __forceinline__ unsigned short f2bf(float f) {
  unsigned u = __float_as_uint(f);
  u = u + 0x7FFF + ((u >> 16) & 1);  // RNE
  return (unsigned short)(u >> 16);
}
__device__ __forceinline__ float bf2f(unsigned short s) {
  return __uint_as_float((unsigned)s << 16);
}

// Lightweight grid barrier: relaxed LLC atomics, no cache flush.
// Preconditions: all blocks co-resident (cooperative launch); all cross-block
// data written via device-scope atomics before the arriving __syncthreads.
__device__ __forceinline__ void gbar(unsigned* ctr, unsigned target) {
  __syncthreads();  // all stats atomics issued + vmcnt drained
  if (threadIdx.x == 0) {
    __hip_atomic_fetch_add(ctr, 1u, __ATOMIC_RELAXED, __HIP_MEMORY_SCOPE_AGENT);
    while (__hip_atomic_load(ctr, __ATOMIC_RELAXED, __HIP_MEMORY_SCOPE_AGENT) < target)
      __builtin_amdgcn_s_sleep(8);
    asm volatile("" ::: "memory");  // no plain loads hoisted above the spin
  }
  __syncthreads();
}

// H36M 16-joint adjacency + diag, row bitmasks (bit j set if mask[i][j])
__constant__ unsigned short kMaskBits[16] = {
    0x0093, 0x0007, 0x000E, 0x000C, 0x0031, 0x0070, 0x0060, 0x0181,
    0x4B80, 0x0700, 0x0600, 0x1900, 0x3800, 0x3000, 0xC100, 0xC000};

// 15 att slots: 0=in, 1=cat, 2..9=res[0..7], 10..14=out[0..4]
__global__ void att_kernel(const float* __restrict__ e_in,
                           const float* __restrict__ e_cat,
                           const float* __restrict__ e_res,
                           const float* __restrict__ e_out,
                           float* __restrict__ att_off,
                           float* __restrict__ attd) {
  int t = threadIdx.x;
  if (t >= 240) return;
  int m = t >> 4, i = t & 15;
  const float* e;
  if (m == 0) e = e_in;
  else if (m == 1) e = e_cat;
  else if (m < 10) e = e_res + (m - 2) * 256;
  else e = e_out + (m - 10) * 256;
  unsigned msk = kMaskBits[i];
  float mx = -3.0e38f;
  for (int j = 0; j < 16; ++j)
    if ((msk >> j) & 1) mx = fmaxf(mx, e[i * 16 + j]);
  float v[16];
  float s = 0.0f;
  for (int j = 0; j < 16; ++j) {
    float val = ((msk >> j) & 1) ? expf(e[i * 16 + j] - mx) : 0.0f;
    v[j] = val;
    s += val;
  }
  float inv = 1.0f / s;
  for (int j = 0; j < 16; ++j)
    att_off[m * 256 + i * 16 + j] = (j == i) ? 0.0f : v[j] * inv;
  attd[m * 16 + i] = v[i] * inv;
}

// att -> bf16 B-fragments for mfma_16x16x16: B[k=(l>>4)*4+j][n=l&15].
// slot layout: [2][64][4] bf16 (Bd then Boff), stride 512 shorts.
__global__ void pack_attB(const float* __restrict__ att_off,
                          const float* __restrict__ attd,
                          short* __restrict__ attB) {
  int idx = blockIdx.x * 256 + threadIdx.x;
  if (idx >= 15 * 64) return;
  int slot = idx >> 6, lane = idx & 63;
  int n = lane & 15, q = lane >> 4;
  frag16 bd, bo;
#pragma unroll
  for (int j = 0; j < 4; ++j) {
    int k = q * 4 + j;
    bd[j] = (short)f2bf(k == n ? attd[slot * 16 + n] : 0.0f);
    bo[j] = (short)f2bf(att_off[slot * 256 + n * 16 + k]);  // attoff^T[k][n]
  }
  *(frag16*)(attB + slot * 512 + lane * 4) = bd;
  *(frag16*)(attB + slot * 512 + 256 + lane * 4) = bo;
}

// W_res[8][2][128][128] fp32 -> bf16 B-fragments (16x16x32).
__global__ void pack_w_kernel(const float* __restrict__ W_res,
                              short* __restrict__ Wpk) {
  int idx = blockIdx.x * 256 + threadIdx.x;  // 8*64*64 = 32768
  int lane = idx & 63;
  int frag = (idx >> 6) & 63;  // kk*16+nt
  int layer = idx >> 12;
  int kk = frag >> 4, nt = frag & 15;
  int n = nt * 16 + (lane & 15);
  int kbase = kk * 32 + (lane >> 4) * 8;
  int mat = n >> 7, c = n & 127;
  const float* Wsrc = W_res + (((size_t)layer * 2 + mat) * 128) * 128;
  short* dst = Wpk + ((size_t)(layer * 64 + frag)) * 512 + lane * 8;
#pragma unroll
  for (int j = 0; j < 8; ++j)
    dst[j] = (short)f2bf(Wsrc[(size_t)(kbase + j) * 128 + c]);
}

// W_out[5][2][128][3] -> bf16 B-frags, N=16: cols 0-2 = W0, 3-5 = W1, rest 0.
__global__ void pack_wout(const float* __restrict__ W_out,
                          short* __restrict__ Wopk) {
  int idx = blockIdx.x * 256 + threadIdx.x;  // 5*4*64 = 1280
  if (idx >= 1280) return;
  int layer = idx >> 8, rem = idx & 255;
  int kk = rem >> 6, lane = rem & 63;
  int n = lane & 15, q = lane >> 4;
  frag_ab v;
#pragma unroll
  for (int j = 0; j < 8; ++j) {
    int k = kk * 32 + q * 8 + j;
    float val = 0.0f;
    if (n < 3) val = W_out[((size_t)(layer * 2 + 0) * 128 + k) * 3 + n];
    else if (n < 6) val = W_out[((size_t)(layer * 2 + 1) * 128 + k) * 3 + (n - 3)];
    v[j] = (short)f2bf(val);
  }
  *(frag_ab*)(Wopk + ((size_t)(layer * 4 + kk) * 64 + lane) * 8) = v;
}

// ---------------------------------------------------------------------------
// LEGACY heavy layer (fallback path only).
// ---------------------------------------------------------------------------
__launch_bounds__(256, 3)
__global__ void gconv_mfma_kernel(const u16* __restrict__ hin,
                                  const float* __restrict__ stats_in,
                                  const float* __restrict__ gamma,
                                  const float* __restrict__ beta,
                                  u16* __restrict__ resbuf,
                                  int res_mode,
                                  const short* __restrict__ Wpk,
                                  const float* __restrict__ bias,
                                  const short* __restrict__ attB,
                                  u16* __restrict__ hout,
                                  float* __restrict__ stats_out) {
  __shared__ short Apk[32 * 512];
  __shared__ float sc_s[128], sh_s[128];

  int tid = threadIdx.x;
  int wv = tid >> 6, lane = tid & 63;
  int q = lane >> 4, m = lane & 15;
  int b0 = blockIdx.x * 8;
  int slice = blockIdx.x & (NSLICE - 1);

  frag16 bd = *(const frag16*)(attB + lane * 4);
  frag16 boff = *(const frag16*)(attB + 256 + lane * 4);
  float biasr[2][4];
  *(float4*)biasr[0] = *(const float4*)(bias + wv * 16 + q * 4);
  *(float4*)biasr[1] = *(const float4*)(bias + 64 + wv * 16 + q * 4);

  if (tid < 128) {
    float sum = 0.f, sq = 0.f;
#pragma unroll
    for (int s = 0; s < NSLICE; ++s) {
      sum += stats_in[s * 256 + tid];
      sq += stats_in[s * 256 + 128 + tid];
    }
    const float invN = 1.0f / (float)NROWS;
    float mu = sum * invN;
    float var = fmaxf(sq * invN - mu * mu, 0.f);
    float sc = gamma[tid] * rsqrtf(var + 1e-5f);
    sc_s[tid] = sc;
    sh_s[tid] = beta[tid] - mu * sc;
  }
  __syncthreads();

#pragma unroll
  for (int mi = 0; mi < 2; ++mi) {
    int mt = wv * 2 + mi;
    size_t bb = (size_t)(b0 + mt) * 2048;
#pragma unroll
    for (int kk = 0; kk < 4; ++kk) {
      size_t base = bb + kk * 512 + q * 128 + m * 8;
      frag_ab hv = *(const frag_ab*)(hin + base);
      const float* scp = &sc_s[kk * 32 + q * 8];
      const float* shp = &sh_s[kk * 32 + q * 8];
      float a[8];
#pragma unroll
      for (int e = 0; e < 8; ++e)
        a[e] = fmaxf(0.f, fmaf(bf2f((unsigned short)hv[e]), scp[e], shp[e]));
      if (res_mode & 1) {
        frag_ab rv = *(const frag_ab*)(resbuf + base);
#pragma unroll
        for (int e = 0; e < 8; ++e) a[e] += bf2f((unsigned short)rv[e]);
      }
      frag_ab av;
#pragma unroll
      for (int e = 0; e < 8; ++e) av[e] = (short)f2bf(a[e]);
      *(frag_ab*)&Apk[(mt * 4 + kk) * 512 + lane * 8] = av;
      if (res_mode & 2) *(frag_ab*)(resbuf + base) = av;
    }
  }
  __syncthreads();

  float ssum[2][4] = {{0.f}}, ssq[2][4] = {{0.f}};
  for (int half = 0; half < 2; ++half) {
    frag_cd acc[4][4];
#pragma unroll
    for (int mi = 0; mi < 4; ++mi)
#pragma unroll
      for (int t = 0; t < 4; ++t) acc[mi][t] = (frag_cd){0.f, 0.f, 0.f, 0.f};

#pragma unroll
    for (int kk = 0; kk < 4; ++kk) {
      frag_ab bfr[4];
#pragma unroll
      for (int t = 0; t < 4; ++t) {
        int nt = wv + 4 * t;
        bfr[t] = *(const frag_ab*)(Wpk + ((kk * 16 + nt) * 64 + lane) * 8);
      }
#pragma unroll
      for (int mi = 0; mi < 4; ++mi) {
        frag_ab af = *(const frag_ab*)&Apk[((half * 4 + mi) * 4 + kk) * 512 + lane * 8];
#pragma unroll
        for (int t = 0; t < 4; ++t)
          acc[mi][t] = __builtin_amdgcn_mfma_f32_16x16x32_bf16(af, bfr[t],
                                                               acc[mi][t], 0, 0, 0);
      }
    }

#pragma unroll
    for (int mi = 0; mi < 4; ++mi) {
      size_t bb = (size_t)(b0 + half * 4 + mi) * 2048;
#pragma unroll
      for (int p = 0; p < 2; ++p) {
        frag16 a0, a1;
#pragma unroll
        for (int r = 0; r < 4; ++r) {
          a0[r] = (short)f2bf(acc[mi][p][r]);
          a1[r] = (short)f2bf(acc[mi][p + 2][r]);
        }
        frag_cd d = (frag_cd){0.f, 0.f, 0.f, 0.f};
        d = __builtin_amdgcn_mfma_f32_16x16x16bf16_1k(a0, bd, d, 0, 0, 0);
        d = __builtin_amdgcn_mfma_f32_16x16x16bf16_1k(a1, boff, d, 0, 0, 0);
        int colbase = (p == 0) ? wv * 16 : 64 + wv * 16;
        frag16 sv;
#pragma unroll
        for (int r = 0; r < 4; ++r) {
          float v = d[r] + biasr[p][r];
          ssum[p][r] += v;
          ssq[p][r] = fmaf(v, v, ssq[p][r]);
          sv[r] = (short)f2bf(v);
        }
        size_t addr = bb + (size_t)(colbase / 8 + (q >> 1)) * 128 + m * 8 + (q & 1) * 4;
        *(frag16*)(hout + addr) = sv;
      }
    }
  }

#pragma unroll
  for (int p = 0; p < 2; ++p)
#pragma unroll
    for (int r = 0; r < 4; ++r) {
      float v1 = ssum[p][r], v2 = ssq[p][r];
      v1 += __shfl_xor(v1, 1); v2 += __shfl_xor(v2, 1);
      v1 += __shfl_xor(v1, 2); v2 += __shfl_xor(v2, 2);
      v1 += __shfl_xor(v1, 4); v2 += __shfl_xor(v2, 4);
      v1 += __shfl_xor(v1, 8); v2 += __shfl_xor(v2, 8);
      if (m == 0) {
        int c = ((p == 0) ? wv * 16 : 64 + wv * 16) + q * 4 + r;
        atomicAdd(&stats_out[slice * 256 + c], v1);
        atomicAdd(&stats_out[slice * 256 + 128 + c], v2);
      }
    }
}

// ---------------------------------------------------------------------------
// Small-K layers (Fin=2, Fin=12): fp32 VALU, blocked bf16 output via LDS.
// ---------------------------------------------------------------------------
template <int FIN>
__launch_bounds__(256)
__global__ void gconv_kernel(const float* __restrict__ hin,
                             const float* __restrict__ W,
                             const float* __restrict__ bias,
                             const float* __restrict__ attoff,
                             const float* __restrict__ attd_p,
                             u16* __restrict__ hout,
                             float* __restrict__ stats_out) {
  __shared__ float xin[2][NJ][FIN];
  __shared__ float att_s[256];
  __shared__ float attd_s[16];
  __shared__ float red[256];
  __shared__ short xout[2][NJ][128];

  int tid = threadIdx.x;
  int b0 = blockIdx.x * 2;
  int slice = blockIdx.x & (NSLICE - 1);

  att_s[tid] = attoff[tid];
  if (tid < 16) attd_s[tid] = attd_p[tid];

  const int TOT4 = 2 * NJ * FIN / 4;
  const float4* hin4 = (const float4*)(hin + (size_t)b0 * NJ * FIN);
  for (int k = tid; k < TOT4; k += 256)
    ((float4*)&xin[0][0][0])[k] = hin4[k];
  __syncthreads();

  int o = tid & 127;
  int bl = tid >> 7;
  float acc0[16], acc1[16];
#pragma unroll
  for (int j = 0; j < 16; ++j) { acc0[j] = 0.0f; acc1[j] = 0.0f; }
  const float* W0 = W;
  const float* W1 = W + FIN * FHID;
  if constexpr (FIN % 4 == 0) {
    for (int f = 0; f < FIN; f += 4) {
      float w00 = W0[(f + 0) * FHID + o], w01 = W0[(f + 1) * FHID + o];
      float w02 = W0[(f + 2) * FHID + o], w03 = W0[(f + 3) * FHID + o];
      float w10 = W1[(f + 0) * FHID + o], w11 = W1[(f + 1) * FHID + o];
      float w12 = W1[(f + 2) * FHID + o], w13 = W1[(f + 3) * FHID + o];
#pragma unroll
      for (int j = 0; j < 16; ++j) {
        float4 xv = *(const float4*)&xin[bl][j][f];
        acc0[j] = fmaf(xv.x, w00, fmaf(xv.y, w01, fmaf(xv.z, w02, fmaf(xv.w, w03, acc0[j]))));
        acc1[j] = fmaf(xv.x, w10, fmaf(xv.y, w11, fmaf(xv.z, w12, fmaf(xv.w, w13, acc1[j]))));
      }
    }
  } else {
    for (int f = 0; f < FIN; ++f) {
      float w0 = W0[f * FHID + o], w1 = W1[f * FHID + o];
#pragma unroll
      for (int j = 0; j < 16; ++j) {
        float xv = xin[bl][j][f];
        acc0[j] = fmaf(xv, w0, acc0[j]);
        acc1[j] = fmaf(xv, w1, acc1[j]);
      }
    }
  }

  float bo = bias[o];
  float ssum = 0.0f, ssq = 0.0f;
#pragma unroll
  for (int i = 0; i < 16; ++i) {
    float h = fmaf(attd_s[i], acc0[i], bo);
#pragma unroll
    for (int j = 0; j < 16; ++j) h = fmaf(att_s[i * 16 + j], acc1[j], h);
    xout[bl][i][o] = (short)f2bf(h);
    ssum += h;
    ssq = fmaf(h, h, ssq);
  }
  __syncthreads();
  red[tid] = ssum;
  __syncthreads();
  if (bl == 0) atomicAdd(&stats_out[slice * 256 + o], ssum + red[o + 128]);
  __syncthreads();
  red[tid] = ssq;
  __syncthreads();
  if (bl == 0) atomicAdd(&stats_out[slice * 256 + 128 + o], ssq + red[o + 128]);
  __syncthreads();

  for (int qq = tid; qq < 512; qq += 256) {
    int b_l = qq >> 8, g = (qq >> 4) & 15, ii = qq & 15;
    *(frag_ab*)(hout + (size_t)(b0 + b_l) * 2048 + g * 128 + ii * 8) =
        *(const frag_ab*)&xout[b_l][ii][g * 8];
  }
}

// ---------------------------------------------------------------------------
// LEGACY output gconv (fallback path only).
// ---------------------------------------------------------------------------
__launch_bounds__(256, 4)
__global__ void gconv_out_kernel(const u16* __restrict__ hin,
                                 const float* __restrict__ stats_in,
                                 const float* __restrict__ gamma,
                                 const float* __restrict__ beta,
                                 const u16* __restrict__ resbuf,
                                 const short* __restrict__ Wopk,
                                 const float* __restrict__ bias,
                                 const float* __restrict__ attoff,
                                 const float* __restrict__ attd_p,
                                 float* __restrict__ out) {
  __shared__ float sc_s[128], sh_s[128];
  __shared__ float att_s[256];
  __shared__ float attd_s[16];
  __shared__ float ys[4][6][16];

  int tid = threadIdx.x;
  int wv = tid >> 6, lane = tid & 63;
  int q = lane >> 4, m = lane & 15;
  int b0 = blockIdx.x * 8;

  att_s[tid] = attoff[tid];
  if (tid < 16) attd_s[tid] = attd_p[tid];
  if (tid < 128) {
    float sum = 0.f, sq = 0.f;
#pragma unroll
    for (int s = 0; s < NSLICE; ++s) {
      sum += stats_in[s * 256 + tid];
      sq += stats_in[s * 256 + 128 + tid];
    }
    const float invN = 1.0f / (float)NROWS;
    float mu = sum * invN;
    float var = fmaxf(sq * invN - mu * mu, 0.f);
    float sc = gamma[tid] * rsqrtf(var + 1e-5f);
    sc_s[tid] = sc;
    sh_s[tid] = beta[tid] - mu * sc;
  }
  __syncthreads();

  frag_ab bfr[4];
#pragma unroll
  for (int kk = 0; kk < 4; ++kk)
    bfr[kk] = *(const frag_ab*)(Wopk + (kk * 64 + lane) * 8);

  for (int mi = 0; mi < 2; ++mi) {
    int b = b0 + wv * 2 + mi;
    size_t bb = (size_t)b * 2048;
    frag_cd acc = (frag_cd){0.f, 0.f, 0.f, 0.f};
#pragma unroll
    for (int kk = 0; kk < 4; ++kk) {
      size_t base = bb + kk * 512 + q * 128 + m * 8;
      frag_ab hv = *(const frag_ab*)(hin + base);
      frag_ab rv = *(const frag_ab*)(resbuf + base);
      const float* scp = &sc_s[kk * 32 + q * 8];
      const float* shp = &sh_s[kk * 32 + q * 8];
      frag_ab av;
#pragma unroll
      for (int e = 0; e < 8; ++e) {
        float a = fmaxf(0.f, fmaf(bf2f((unsigned short)hv[e]), scp[e], shp[e])) +
                  bf2f((unsigned short)rv[e]);
        av[e] = (short)f2bf(a);
      }
      acc = __builtin_amdgcn_mfma_f32_16x16x32_bf16(av, bfr[kk], acc, 0, 0, 0);
    }
    if (m < 6) {
#pragma unroll
      for (int r = 0; r < 4; ++r) ys[wv][m][q * 4 + r] = acc[r];
    }
    if (q < 3) {
      float v = bias[q] + attd_s[m] * ys[wv][q][m];
#pragma unroll
      for (int j = 0; j < 16; ++j) v = fmaf(att_s[m * 16 + j], ys[wv][3 + q][j], v);
      out[((size_t)b * 16 + m) * 3 + q] = v;
    }
  }
}

// ---------------------------------------------------------------------------
// Fused res-stack + out layer. Cooperative, grid 1024 x 256 (8 rows/block,
// 4 blocks/CU). Designed to fit the 128-VGPR tier: R=32, acc=32.
// ---------------------------------------------------------------------------
__launch_bounds__(256, 4)
__global__ void stack_fused_kernel(
    const u16* __restrict__ hbuf,       // blocked bf16 input h0 [8192][2048]
    float* __restrict__ stats,          // 9 stages x [32][256]; stage0 pre-filled
    unsigned* __restrict__ bar,         // this launch's barrier counter (zeroed)
    const float* __restrict__ g0,       // layer-0 gamma
    const float* __restrict__ bt0,      // layer-0 beta
    const float* __restrict__ g_res,    // [8][128]
    const float* __restrict__ beta_res, // [8][128]
    const float* __restrict__ b_res,    // [8][128]
    const short* __restrict__ Wpk,      // [8][64][64][8]
    const short* __restrict__ attB,     // slot base; res layer k at (2+k)*512
    const short* __restrict__ Wopk_l,   // [4][64][8] this stack's out layer
    const float* __restrict__ bias_out, // [3]
    const float* __restrict__ attoff_o, // [256]
    const float* __restrict__ attd_o,   // [16]
    float* __restrict__ out)            // [8192][16][3]
{
  __shared__ short Hs[16384];           // 8 batch x 2048 bf16 (32 KB)
  __shared__ float sc_s[128], sh_s[128];
  __shared__ float att_s[256];
  __shared__ float attd_s[16];
  __shared__ float ys[4][6][16];

  const int tid = threadIdx.x;
  const int wv = tid >> 6, lane = tid & 63;
  const int q = lane >> 4, m = lane & 15;
  const int b0 = blockIdx.x * 8;
  const int slice = blockIdx.x & (NSLICE - 1);

  att_s[tid] = attoff_o[tid];
  if (tid < 16) attd_s[tid] = attd_o[tid];

  frag_ab R[2][4];  // residual, thread-owned frags (row = wv*2+b4, kk): 32 VGPR

  // preload h0 into LDS: thread's own 8 fragments, 16B/lane coalesced
#pragma unroll
  for (int b4 = 0; b4 < 2; ++b4)
#pragma unroll
    for (int kk = 0; kk < 4; ++kk) {
      int off = ((wv * 2 + b4) * 4 + kk) * 512 + lane * 8;
      *(frag_ab*)&Hs[off] = *(const frag_ab*)(hbuf + (size_t)b0 * 2048 + off);
    }

#pragma unroll 1
  for (int k = 0; k < 8; ++k) {
    if (k) gbar(bar, 1024u * (unsigned)k);

    // ---- phase 0: reduce BN stats stage k -> scale/shift in LDS ----
    const float* st = stats + (size_t)k * (NSLICE * 256);
    const float* gg = k ? g_res + (size_t)(k - 1) * 128 : g0;
    const float* bt = k ? beta_res + (size_t)(k - 1) * 128 : bt0;
    if (tid < 128) {
      float sum = 0.f, sq = 0.f;
#pragma unroll
      for (int s = 0; s < NSLICE; ++s) {
        sum += st[s * 256 + tid];
        sq += st[s * 256 + 128 + tid];
      }
      const float invN = 1.0f / (float)NROWS;
      float mu = sum * invN;
      float var = fmaxf(sq * invN - mu * mu, 0.f);
      float sc = gg[tid] * rsqrtf(var + 1e-5f);
      sc_s[tid] = sc;
      sh_s[tid] = bt[tid] - mu * sc;
    }
    __syncthreads();

    // ---- phase 1: in-place BN+ReLU(+residual), thread-owned frags ----
    const bool doadd = (k > 0) && ((k & 1) == 0);
    const bool dosave = ((k & 1) == 0);
#pragma unroll
    for (int b4 = 0; b4 < 2; ++b4)
#pragma unroll
      for (int kk = 0; kk < 4; ++kk) {
        int off = ((wv * 2 + b4) * 4 + kk) * 512 + lane * 8;
        frag_ab hv = *(const frag_ab*)&Hs[off];
        const float* scp = &sc_s[kk * 32 + q * 8];
        const float* shp = &sh_s[kk * 32 + q * 8];
        float a[8];
#pragma unroll
        for (int e = 0; e < 8; ++e)
          a[e] = fmaxf(0.f, fmaf(bf2f((unsigned short)hv[e]), scp[e], shp[e]));
        if (doadd) {
#pragma unroll
          for (int e = 0; e < 8; ++e) a[e] += bf2f((unsigned short)R[b4][kk][e]);
        }
        frag_ab av;
#pragma unroll
        for (int e = 0; e < 8; ++e) av[e] = (short)f2bf(a[e]);
        *(frag_ab*)&Hs[off] = av;
        if (dosave) R[b4][kk] = av;
      }
    __syncthreads();

    // ---- phase 2: GEMM + MFMA mix epilogue, 4 groups of 2 m-tiles ----
    const short* Wl = Wpk + (size_t)k * 32768;
    const short* aB = attB + (size_t)(2 + k) * 512;
    frag16 bd = *(const frag16*)(aB + lane * 4);
    frag16 boff = *(const frag16*)(aB + 256 + lane * 4);
    float biasr[2][4];
    *(float4*)biasr[0] = *(const float4*)(b_res + (size_t)k * 128 + wv * 16 + q * 4);
    *(float4*)biasr[1] = *(const float4*)(b_res + (size_t)k * 128 + 64 + wv * 16 + q * 4);

    float ssum[2][4] = {{0.f}}, ssq[2][4] = {{0.f}};
#pragma unroll 1
    for (int g4 = 0; g4 < 4; ++g4) {
      frag_cd acc[2][4];
#pragma unroll
      for (int mi = 0; mi < 2; ++mi)
#pragma unroll
        for (int t = 0; t < 4; ++t) acc[mi][t] = (frag_cd){0.f, 0.f, 0.f, 0.f};

#pragma unroll 1
      for (int kk = 0; kk < 4; ++kk) {
        frag_ab bfr[4];
#pragma unroll
        for (int t = 0; t < 4; ++t)
          bfr[t] = *(const frag_ab*)(Wl + ((kk * 16 + (wv + 4 * t)) * 64 + lane) * 8);
#pragma unroll
        for (int mi = 0; mi < 2; ++mi) {
          frag_ab af = *(const frag_ab*)&Hs[((g4 * 2 + mi) * 4 + kk) * 512 + lane * 8];
#pragma unroll
          for (int t = 0; t < 4; ++t)
            acc[mi][t] = __builtin_amdgcn_mfma_f32_16x16x32_bf16(af, bfr[t],
                                                                 acc[mi][t], 0, 0, 0);
        }
      }
      // all waves done READING rows [2*g4, 2*g4+2) before overwriting with Y
      __syncthreads();
#pragma unroll
      for (int mi = 0; mi < 2; ++mi) {
        int bl = g4 * 2 + mi;
#pragma unroll
        for (int p = 0; p < 2; ++p) {
          frag16 a0, a1;
#pragma unroll
          for (int r = 0; r < 4; ++r) {
            a0[r] = (short)f2bf(acc[mi][p][r]);
            a1[r] = (short)f2bf(acc[mi][p + 2][r]);
          }
          frag_cd d = (frag_cd){0.f, 0.f, 0.f, 0.f};
          d = __builtin_amdgcn_mfma_f32_16x16x16bf16_1k(a0, bd, d, 0, 0, 0);
          d = __builtin_amdgcn_mfma_f32_16x16x16bf16_1k(a1, boff, d, 0, 0, 0);
          int colbase = (p == 0) ? wv * 16 : 64 + wv * 16;
          frag16 sv;
#pragma unroll
          for (int r = 0; r < 4; ++r) {
            float v = d[r] + biasr[p][r];
            ssum[p][r] += v;
            ssq[p][r] = fmaf(v, v, ssq[p][r]);
            sv[r] = (short)f2bf(v);
          }
          *(frag16*)&Hs[bl * 2048 + (colbase / 8 + (q >> 1)) * 128 + m * 8 + (q & 1) * 4] = sv;
        }
      }
      // no barrier needed: group g4+1 MFMA reads are disjoint from these writes
    }

    // ---- phase 3: BN stats -> stage k+1 (device-scope atomics @ LLC) ----
    float* so = stats + (size_t)(k + 1) * (NSLICE * 256);
#pragma unroll
    for (int p = 0; p < 2; ++p)
#pragma unroll
      for (int r = 0; r < 4; ++r) {
        float v1 = ssum[p][r], v2 = ssq[p][r];
        v1 += __shfl_xor(v1, 1); v2 += __shfl_xor(v2, 1);
        v1 += __shfl_xor(v1, 2); v2 += __shfl_xor(v2, 2);
        v1 += __shfl_xor(v1, 4); v2 += __shfl_xor(v2, 4);
        v1 += __shfl_xor(v1, 8); v2 += __shfl_xor(v2, 8);
        if (m == 0) {
          int c = ((p == 0) ? wv * 16 : 64 + wv * 16) + q * 4 + r;
          atomicAdd(&so[slice * 256 + c], v1);
          atomicAdd(&so[slice * 256 + 128 + c], v2);
        }
      }
  }

  // ---- out stage: BN + residual + Fout=3 gconv ----
  gbar(bar, 1024u * 8u);
  {
    const float* st = stats + (size_t)8 * (NSLICE * 256);
    if (tid < 128) {
      float sum = 0.f, sq = 0.f;
#pragma unroll
      for (int s = 0; s < NSLICE; ++s) {
        sum += st[s * 256 + tid];
        sq += st[s * 256 + 128 + tid];
      }
      const float invN = 1.0f / (float)NROWS;
      float mu = sum * invN;
      float var = fmaxf(sq * invN - mu * mu, 0.f);
      float sc = g_res[7 * 128 + tid] * rsqrtf(var + 1e-5f);
      sc_s[tid] = sc;
      sh_s[tid] = beta_res[7 * 128 + tid] - mu * sc;
    }
    __syncthreads();

    frag_ab bfrO[4];
#pragma unroll
    for (int kk = 0; kk < 4; ++kk)
      bfrO[kk] = *(const frag_ab*)(Wopk_l + (kk * 64 + lane) * 8);

    for (int b4 = 0; b4 < 2; ++b4) {
      int bl = wv * 2 + b4;
      int b = b0 + bl;
      frag_cd acc = (frag_cd){0.f, 0.f, 0.f, 0.f};
#pragma unroll
      for (int kk = 0; kk < 4; ++kk) {
        int off = (bl * 4 + kk) * 512 + lane * 8;
        frag_ab hv = *(const frag_ab*)&Hs[off];
        const float* scp = &sc_s[kk * 32 + q * 8];
        const float* shp = &sh_s[kk * 32 + q * 8];
        frag_ab av;
#pragma unroll
        for (int e = 0; e < 8; ++e) {
          float a = fmaxf(0.f, fmaf(bf2f((unsigned short)hv[e]), scp[e], shp[e])) +
                    bf2f((unsigned short)R[b4][kk][e]);
          av[e] = (short)f2bf(a);
        }
        acc = __builtin_amdgcn_mfma_f32_16x16x32_bf16(av, bfrO[kk], acc, 0, 0, 0);
      }
      if (m < 6) {
#pragma unroll
        for (int r = 0; r < 4; ++r) ys[wv][m][q * 4 + r] = acc[r];
      }
      // same-wave LDS ops are in-order; no barrier needed (proven pattern)
      if (q < 3) {
        float v = bias_out[q] + attd_s[m] * ys[wv][q][m];
#pragma unroll
        for (int j = 0; j < 16; ++j) v = fmaf(att_s[m * 16 + j], ys[wv][3 + q][j], v);
        out[((size_t)b * 16 + m) * 3 + q] = v;
      }
    }
  }
}

// merged[b,j,c] = out_{1+c/3}[b,j,c%3]; out_i at d_out + i*393216
__global__ void pack_merged(const float* __restrict__ dout, float* __restrict__ merged) {
  int idx = blockIdx.x * 256 + threadIdx.x;
  if (idx >= BATCH * NJ * 12) return;
  int c = idx % 12;
  int bj = idx / 12;
  merged[idx] = dout[(size_t)(1 + c / 3) * 393216 + (size_t)bj * 3 + (c % 3)];
}

extern "C" void kernel_launch(void* const* d_in, const int* in_sizes, int n_in,
                              void* d_out, int out_size, void* d_ws, size_t ws_size,
                              hipStream_t stream) {
  (void)in_sizes; (void)n_in; (void)out_size; (void)ws_size;
  const float* W_in = (const float*)d_in[4];
  const float* b_in = (const float*)d_in[5];
  const float* e_in = (const float*)d_in[6];
  const float* g_in = (const float*)d_in[7];
  const float* beta_in = (const float*)d_in[8];
  const float* W_cat = (const float*)d_in[9];
  const float* b_cat = (const float*)d_in[10];
  const float* e_cat = (const float*)d_in[11];
  const float* g_cat = (const float*)d_in[12];
  const float* beta_cat = (const float*)d_in[13];
  const float* W_res = (const float*)d_in[14];
  const float* b_res = (const float*)d_in[15];
  const float* e_res = (const float*)d_in[16];
  const float* g_res = (const float*)d_in[17];
  const float* beta_res = (const float*)d_in[18];
  const float* W_out = (const float*)d_in[19];
  const float* b_out = (const float*)d_in[20];
  const float* e_out = (const float*)d_in[21];

  float* ws = (float*)d_ws;
  float* att_off = ws;                          // 3840 fl
  float* attd = att_off + 3840;                 // 240 fl (pad to 256)
  short* attB = (short*)(attd + 256);           // 15*512 shorts
  short* Wpk = attB + 15 * 512;                 // 8*64*512 = 262144 shorts
  short* Wopk = Wpk + 262144;                   // 5*2048 = 10240 shorts
  float* stats = (float*)(Wopk + 10240);        // 45 slots x 32 x 256 fl
  unsigned* barc = (unsigned*)(stats + 45 * NSLICE * 256);  // 64 words (5 ctrs)
  float* merged = stats + 45 * NSLICE * 256 + 64;           // B*16*12 fl
  u16* hbuf = (u16*)(merged + (size_t)BATCH * NJ * 12);  // 16777216 u16
  u16* Rg = hbuf + (size_t)BATCH * NJ * FHID;            // legacy resbuf

  hipMemsetAsync(stats, 0, (45 * NSLICE * 256 + 64) * sizeof(float), stream);
  att_kernel<<<1, 256, 0, stream>>>(e_in, e_cat, e_res, e_out, att_off, attd);
  pack_attB<<<4, 256, 0, stream>>>(att_off, attd, attB);
  pack_w_kernel<<<128, 256, 0, stream>>>(W_res, Wpk);
  pack_wout<<<5, 256, 0, stream>>>(W_out, Wopk);

  float* dout = (float*)d_out;
  const int SSTRIDE = NSLICE * 256;

  int coop = 0, dev = 0;
  hipGetDevice(&dev);
  hipDeviceGetAttribute(&coop, hipDeviceAttributeCooperativeLaunch, dev);

  auto run_stack_legacy = [&](int sb, const float* g0, const float* bt0, int out_layer,
                              const float* bo, int att_out_slot, float* optr) {
    for (int k = 0; k < 8; ++k) {
      const float* gg = (k == 0) ? g0 : g_res + (size_t)(k - 1) * FHID;
      const float* bb = (k == 0) ? bt0 : beta_res + (size_t)(k - 1) * FHID;
      int rm = (k == 0) ? 2 : ((k % 2 == 0) ? 3 : 0);
      gconv_mfma_kernel<<<BATCH / 8, 256, 0, stream>>>(
          hbuf, stats + (size_t)(sb + k) * SSTRIDE, gg, bb, Rg, rm,
          Wpk + (size_t)k * 32768, b_res + (size_t)k * FHID,
          attB + (size_t)(2 + k) * 512, hbuf,
          stats + (size_t)(sb + k + 1) * SSTRIDE);
    }
    gconv_out_kernel<<<BATCH / 8, 256, 0, stream>>>(
        hbuf, stats + (size_t)(sb + 8) * SSTRIDE, g_res + 7 * FHID,
        beta_res + 7 * FHID, Rg, Wopk + (size_t)out_layer * 2048, bo,
        att_off + (size_t)att_out_slot * 256, attd + (size_t)att_out_slot * 16,
        optr);
  };

  int fused_idx = 0;
  auto run_fused = [&](const float* g0p, const float* bt0p, int out_layer,
                       const float* bo, int slot, float* optr, float* st) -> bool {
    if (!coop) return false;
    const u16* a0 = hbuf;
    float* a1 = st;
    unsigned* a2 = barc + fused_idx;
    const float* a3 = g0p;
    const float* a4 = bt0p;
    const float* a5 = g_res;
    const float* a6 = beta_res;
    const float* a7 = b_res;
    const short* a8 = Wpk;
    const short* a9 = attB;
    const short* a10 = Wopk + (size_t)out_layer * 2048;
    const float* a11 = bo;
    const float* a12 = att_off + (size_t)slot * 256;
    const float* a13 = attd + (size_t)slot * 16;
    float* a14 = optr;
    void* args[15] = {&a0, &a1, &a2, &a3, &a4, &a5, &a6, &a7,
                      &a8, &a9, &a10, &a11, &a12, &a13, &a14};
    bool ok = hipLaunchCooperativeKernel((const void*)stack_fused_kernel, dim3(1024),
                                         dim3(256), args, 0, stream) == hipSuccess;
    if (ok) ++fused_idx;
    return ok;
  };

  for (int bi = 0; bi < 4; ++bi) {
    gconv_kernel<2><<<BATCH / 2, 256, 0, stream>>>(
        (const float*)d_in[bi], W_in, b_in, att_off, attd, hbuf,
        stats + (size_t)(bi * 9) * SSTRIDE);
    if (!run_fused(g_in, beta_in, bi, b_out + bi * 3, 10 + bi,
                   dout + (size_t)(1 + bi) * 393216,
                   stats + (size_t)(bi * 9) * SSTRIDE))
      run_stack_legacy(bi * 9, g_in, beta_in, bi, b_out + bi * 3, 10 + bi,
                       dout + (size_t)(1 + bi) * 393216);
  }

  pack_merged<<<(BATCH * NJ * 12 + 255) / 256, 256, 0, stream>>>(dout, merged);
  gconv_kernel<12><<<BATCH / 2, 256, 0, stream>>>(
      merged, W_cat, b_cat, att_off + 256, attd + 16, hbuf,
      stats + (size_t)36 * SSTRIDE);
  if (!run_fused(g_cat, beta_cat, 4, b_out + 12, 14, dout,
                 stats + (size_t)36 * SSTRIDE))
    run_stack_legacy(36, g_cat, beta_cat, 4, b_out + 12, 14, dout);
}

// Round 5
// 1793.567 us; speedup vs baseline: 2.4621x; 2.4621x over previous
//
#include <hip/hip_runtime.h>
#include <hip/hip_bf16.h>
#include <hip/hip_cooperative_groups.h>

namespace cg = cooperative_groups;

// ---------------------------------------------------------------------------
// SemGCN forward, round 8.
//  * Round-7 low-pressure fused res-stack (residual in GLOBAL resbuf, acc=16,
//    peak arch live ~52 regs -> fits the allocator's 64-reg pick, no spills)
//    BUT with cg::grid.sync() instead of the homemade spin barrier:
//    rounds 5/6's gbar produced 21-41ms outlier dispatches under profiling and
//    most likely hung round 7's container. grid.sync was clean in round 4.
//  * RUNTIME GUARD kept: if compiled fused kernel has scratch
//    (localSizeBytes != 0) or cooperative launch unavailable -> proven legacy
//    per-layer path.
// ---------------------------------------------------------------------------

#define BATCH 8192
#define NJ 16
#define FHID 128
#define NROWS (BATCH * NJ)   // 131072
#define NSLICE 32

typedef unsigned short u16;
typedef __attribute__((ext_vector_type(8))) short frag_ab;  // 8 bf16
typedef __attribute__((ext_vector_type(4))) short frag16;   // 4 bf16
typedef __attribute__((ext_vector_type(4))) float frag_cd;  // 4 fp32

__device__ __forceinline__ unsigned short f2bf(float f) {
  unsigned u = __float_as_uint(f);
  u = u + 0x7FFF + ((u >> 16) & 1);  // RNE
  return (unsigned short)(u >> 16);
}
__device__ __forceinline__ float bf2f(unsigned short s) {
  return __uint_as_float((unsigned)s << 16);
}

// H36M 16-joint adjacency + diag, row bitmasks (bit j set if mask[i][j])
__constant__ unsigned short kMaskBits[16] = {
    0x0093, 0x0007, 0x000E, 0x000C, 0x0031, 0x0070, 0x0060, 0x0181,
    0x4B80, 0x0700, 0x0600, 0x1900, 0x3800, 0x3000, 0xC100, 0xC000};

// 15 att slots: 0=in, 1=cat, 2..9=res[0..7], 10..14=out[0..4]
__global__ void att_kernel(const float* __restrict__ e_in,
                           const float* __restrict__ e_cat,
                           const float* __restrict__ e_res,
                           const float* __restrict__ e_out,
                           float* __restrict__ att_off,
                           float* __restrict__ attd) {
  int t = threadIdx.x;
  if (t >= 240) return;
  int m = t >> 4, i = t & 15;
  const float* e;
  if (m == 0) e = e_in;
  else if (m == 1) e = e_cat;
  else if (m < 10) e = e_res + (m - 2) * 256;
  else e = e_out + (m - 10) * 256;
  unsigned msk = kMaskBits[i];
  float mx = -3.0e38f;
  for (int j = 0; j < 16; ++j)
    if ((msk >> j) & 1) mx = fmaxf(mx, e[i * 16 + j]);
  float v[16];
  float s = 0.0f;
  for (int j = 0; j < 16; ++j) {
    float val = ((msk >> j) & 1) ? expf(e[i * 16 + j] - mx) : 0.0f;
    v[j] = val;
    s += val;
  }
  float inv = 1.0f / s;
  for (int j = 0; j < 16; ++j)
    att_off[m * 256 + i * 16 + j] = (j == i) ? 0.0f : v[j] * inv;
  attd[m * 16 + i] = v[i] * inv;
}

// att -> bf16 B-fragments for mfma_16x16x16: B[k=(l>>4)*4+j][n=l&15].
__global__ void pack_attB(const float* __restrict__ att_off,
                          const float* __restrict__ attd,
                          short* __restrict__ attB) {
  int idx = blockIdx.x * 256 + threadIdx.x;
  if (idx >= 15 * 64) return;
  int slot = idx >> 6, lane = idx & 63;
  int n = lane & 15, q = lane >> 4;
  frag16 bd, bo;
#pragma unroll
  for (int j = 0; j < 4; ++j) {
    int k = q * 4 + j;
    bd[j] = (short)f2bf(k == n ? attd[slot * 16 + n] : 0.0f);
    bo[j] = (short)f2bf(att_off[slot * 256 + n * 16 + k]);  // attoff^T[k][n]
  }
  *(frag16*)(attB + slot * 512 + lane * 4) = bd;
  *(frag16*)(attB + slot * 512 + 256 + lane * 4) = bo;
}

// W_res[8][2][128][128] fp32 -> bf16 B-fragments (16x16x32).
__global__ void pack_w_kernel(const float* __restrict__ W_res,
                              short* __restrict__ Wpk) {
  int idx = blockIdx.x * 256 + threadIdx.x;  // 8*64*64 = 32768
  int lane = idx & 63;
  int frag = (idx >> 6) & 63;  // kk*16+nt
  int layer = idx >> 12;
  int kk = frag >> 4, nt = frag & 15;
  int n = nt * 16 + (lane & 15);
  int kbase = kk * 32 + (lane >> 4) * 8;
  int mat = n >> 7, c = n & 127;
  const float* Wsrc = W_res + (((size_t)layer * 2 + mat) * 128) * 128;
  short* dst = Wpk + ((size_t)(layer * 64 + frag)) * 512 + lane * 8;
#pragma unroll
  for (int j = 0; j < 8; ++j)
    dst[j] = (short)f2bf(Wsrc[(size_t)(kbase + j) * 128 + c]);
}

// W_out[5][2][128][3] -> bf16 B-frags, N=16: cols 0-2 = W0, 3-5 = W1, rest 0.
__global__ void pack_wout(const float* __restrict__ W_out,
                          short* __restrict__ Wopk) {
  int idx = blockIdx.x * 256 + threadIdx.x;  // 5*4*64 = 1280
  if (idx >= 1280) return;
  int layer = idx >> 8, rem = idx & 255;
  int kk = rem >> 6, lane = rem & 63;
  int n = lane & 15, q = lane >> 4;
  frag_ab v;
#pragma unroll
  for (int j = 0; j < 8; ++j) {
    int k = kk * 32 + q * 8 + j;
    float val = 0.0f;
    if (n < 3) val = W_out[((size_t)(layer * 2 + 0) * 128 + k) * 3 + n];
    else if (n < 6) val = W_out[((size_t)(layer * 2 + 1) * 128 + k) * 3 + (n - 3)];
    v[j] = (short)f2bf(val);
  }
  *(frag_ab*)(Wopk + ((size_t)(layer * 4 + kk) * 64 + lane) * 8) = v;
}

// ---------------------------------------------------------------------------
// LEGACY heavy layer (fallback path).
// ---------------------------------------------------------------------------
__launch_bounds__(256, 3)
__global__ void gconv_mfma_kernel(const u16* __restrict__ hin,
                                  const float* __restrict__ stats_in,
                                  const float* __restrict__ gamma,
                                  const float* __restrict__ beta,
                                  u16* __restrict__ resbuf,
                                  int res_mode,
                                  const short* __restrict__ Wpk,
                                  const float* __restrict__ bias,
                                  const short* __restrict__ attB,
                                  u16* __restrict__ hout,
                                  float* __restrict__ stats_out) {
  __shared__ short Apk[32 * 512];
  __shared__ float sc_s[128], sh_s[128];

  int tid = threadIdx.x;
  int wv = tid >> 6, lane = tid & 63;
  int q = lane >> 4, m = lane & 15;
  int b0 = blockIdx.x * 8;
  int slice = blockIdx.x & (NSLICE - 1);

  frag16 bd = *(const frag16*)(attB + lane * 4);
  frag16 boff = *(const frag16*)(attB + 256 + lane * 4);
  float biasr[2][4];
  *(float4*)biasr[0] = *(const float4*)(bias + wv * 16 + q * 4);
  *(float4*)biasr[1] = *(const float4*)(bias + 64 + wv * 16 + q * 4);

  if (tid < 128) {
    float sum = 0.f, sq = 0.f;
#pragma unroll
    for (int s = 0; s < NSLICE; ++s) {
      sum += stats_in[s * 256 + tid];
      sq += stats_in[s * 256 + 128 + tid];
    }
    const float invN = 1.0f / (float)NROWS;
    float mu = sum * invN;
    float var = fmaxf(sq * invN - mu * mu, 0.f);
    float sc = gamma[tid] * rsqrtf(var + 1e-5f);
    sc_s[tid] = sc;
    sh_s[tid] = beta[tid] - mu * sc;
  }
  __syncthreads();

#pragma unroll
  for (int mi = 0; mi < 2; ++mi) {
    int mt = wv * 2 + mi;
    size_t bb = (size_t)(b0 + mt) * 2048;
#pragma unroll
    for (int kk = 0; kk < 4; ++kk) {
      size_t base = bb + kk * 512 + q * 128 + m * 8;
      frag_ab hv = *(const frag_ab*)(hin + base);
      const float* scp = &sc_s[kk * 32 + q * 8];
      const float* shp = &sh_s[kk * 32 + q * 8];
      float a[8];
#pragma unroll
      for (int e = 0; e < 8; ++e)
        a[e] = fmaxf(0.f, fmaf(bf2f((unsigned short)hv[e]), scp[e], shp[e]));
      if (res_mode & 1) {
        frag_ab rv = *(const frag_ab*)(resbuf + base);
#pragma unroll
        for (int e = 0; e < 8; ++e) a[e] += bf2f((unsigned short)rv[e]);
      }
      frag_ab av;
#pragma unroll
      for (int e = 0; e < 8; ++e) av[e] = (short)f2bf(a[e]);
      *(frag_ab*)&Apk[(mt * 4 + kk) * 512 + lane * 8] = av;
      if (res_mode & 2) *(frag_ab*)(resbuf + base) = av;
    }
  }
  __syncthreads();

  float ssum[2][4] = {{0.f}}, ssq[2][4] = {{0.f}};
  for (int half = 0; half < 2; ++half) {
    frag_cd acc[4][4];
#pragma unroll
    for (int mi = 0; mi < 4; ++mi)
#pragma unroll
      for (int t = 0; t < 4; ++t) acc[mi][t] = (frag_cd){0.f, 0.f, 0.f, 0.f};

#pragma unroll
    for (int kk = 0; kk < 4; ++kk) {
      frag_ab bfr[4];
#pragma unroll
      for (int t = 0; t < 4; ++t) {
        int nt = wv + 4 * t;
        bfr[t] = *(const frag_ab*)(Wpk + ((kk * 16 + nt) * 64 + lane) * 8);
      }
#pragma unroll
      for (int mi = 0; mi < 4; ++mi) {
        frag_ab af = *(const frag_ab*)&Apk[((half * 4 + mi) * 4 + kk) * 512 + lane * 8];
#pragma unroll
        for (int t = 0; t < 4; ++t)
          acc[mi][t] = __builtin_amdgcn_mfma_f32_16x16x32_bf16(af, bfr[t],
                                                               acc[mi][t], 0, 0, 0);
      }
    }

#pragma unroll
    for (int mi = 0; mi < 4; ++mi) {
      size_t bb = (size_t)(b0 + half * 4 + mi) * 2048;
#pragma unroll
      for (int p = 0; p < 2; ++p) {
        frag16 a0, a1;
#pragma unroll
        for (int r = 0; r < 4; ++r) {
          a0[r] = (short)f2bf(acc[mi][p][r]);
          a1[r] = (short)f2bf(acc[mi][p + 2][r]);
        }
        frag_cd d = (frag_cd){0.f, 0.f, 0.f, 0.f};
        d = __builtin_amdgcn_mfma_f32_16x16x16bf16_1k(a0, bd, d, 0, 0, 0);
        d = __builtin_amdgcn_mfma_f32_16x16x16bf16_1k(a1, boff, d, 0, 0, 0);
        int colbase = (p == 0) ? wv * 16 : 64 + wv * 16;
        frag16 sv;
#pragma unroll
        for (int r = 0; r < 4; ++r) {
          float v = d[r] + biasr[p][r];
          ssum[p][r] += v;
          ssq[p][r] = fmaf(v, v, ssq[p][r]);
          sv[r] = (short)f2bf(v);
        }
        size_t addr = bb + (size_t)(colbase / 8 + (q >> 1)) * 128 + m * 8 + (q & 1) * 4;
        *(frag16*)(hout + addr) = sv;
      }
    }
  }

#pragma unroll
  for (int p = 0; p < 2; ++p)
#pragma unroll
    for (int r = 0; r < 4; ++r) {
      float v1 = ssum[p][r], v2 = ssq[p][r];
      v1 += __shfl_xor(v1, 1); v2 += __shfl_xor(v2, 1);
      v1 += __shfl_xor(v1, 2); v2 += __shfl_xor(v2, 2);
      v1 += __shfl_xor(v1, 4); v2 += __shfl_xor(v2, 4);
      v1 += __shfl_xor(v1, 8); v2 += __shfl_xor(v2, 8);
      if (m == 0) {
        int c = ((p == 0) ? wv * 16 : 64 + wv * 16) + q * 4 + r;
        atomicAdd(&stats_out[slice * 256 + c], v1);
        atomicAdd(&stats_out[slice * 256 + 128 + c], v2);
      }
    }
}

// ---------------------------------------------------------------------------
// Small-K layers (Fin=2, Fin=12): fp32 VALU, blocked bf16 output via LDS.
// ---------------------------------------------------------------------------
template <int FIN>
__launch_bounds__(256)
__global__ void gconv_kernel(const float* __restrict__ hin,
                             const float* __restrict__ W,
                             const float* __restrict__ bias,
                             const float* __restrict__ attoff,
                             const float* __restrict__ attd_p,
                             u16* __restrict__ hout,
                             float* __restrict__ stats_out) {
  __shared__ float xin[2][NJ][FIN];
  __shared__ float att_s[256];
  __shared__ float attd_s[16];
  __shared__ float red[256];
  __shared__ short xout[2][NJ][128];

  int tid = threadIdx.x;
  int b0 = blockIdx.x * 2;
  int slice = blockIdx.x & (NSLICE - 1);

  att_s[tid] = attoff[tid];
  if (tid < 16) attd_s[tid] = attd_p[tid];

  const int TOT4 = 2 * NJ * FIN / 4;
  const float4* hin4 = (const float4*)(hin + (size_t)b0 * NJ * FIN);
  for (int k = tid; k < TOT4; k += 256)
    ((float4*)&xin[0][0][0])[k] = hin4[k];
  __syncthreads();

  int o = tid & 127;
  int bl = tid >> 7;
  float acc0[16], acc1[16];
#pragma unroll
  for (int j = 0; j < 16; ++j) { acc0[j] = 0.0f; acc1[j] = 0.0f; }
  const float* W0 = W;
  const float* W1 = W + FIN * FHID;
  if constexpr (FIN % 4 == 0) {
    for (int f = 0; f < FIN; f += 4) {
      float w00 = W0[(f + 0) * FHID + o], w01 = W0[(f + 1) * FHID + o];
      float w02 = W0[(f + 2) * FHID + o], w03 = W0[(f + 3) * FHID + o];
      float w10 = W1[(f + 0) * FHID + o], w11 = W1[(f + 1) * FHID + o];
      float w12 = W1[(f + 2) * FHID + o], w13 = W1[(f + 3) * FHID + o];
#pragma unroll
      for (int j = 0; j < 16; ++j) {
        float4 xv = *(const float4*)&xin[bl][j][f];
        acc0[j] = fmaf(xv.x, w00, fmaf(xv.y, w01, fmaf(xv.z, w02, fmaf(xv.w, w03, acc0[j]))));
        acc1[j] = fmaf(xv.x, w10, fmaf(xv.y, w11, fmaf(xv.z, w12, fmaf(xv.w, w13, acc1[j]))));
      }
    }
  } else {
    for (int f = 0; f < FIN; ++f) {
      float w0 = W0[f * FHID + o], w1 = W1[f * FHID + o];
#pragma unroll
      for (int j = 0; j < 16; ++j) {
        float xv = xin[bl][j][f];
        acc0[j] = fmaf(xv, w0, acc0[j]);
        acc1[j] = fmaf(xv, w1, acc1[j]);
      }
    }
  }

  float bo = bias[o];
  float ssum = 0.0f, ssq = 0.0f;
#pragma unroll
  for (int i = 0; i < 16; ++i) {
    float h = fmaf(attd_s[i], acc0[i], bo);
#pragma unroll
    for (int j = 0; j < 16; ++j) h = fmaf(att_s[i * 16 + j], acc1[j], h);
    xout[bl][i][o] = (short)f2bf(h);
    ssum += h;
    ssq = fmaf(h, h, ssq);
  }
  __syncthreads();
  red[tid] = ssum;
  __syncthreads();
  if (bl == 0) atomicAdd(&stats_out[slice * 256 + o], ssum + red[o + 128]);
  __syncthreads();
  red[tid] = ssq;
  __syncthreads();
  if (bl == 0) atomicAdd(&stats_out[slice * 256 + 128 + o], ssq + red[o + 128]);
  __syncthreads();

  for (int qq = tid; qq < 512; qq += 256) {
    int b_l = qq >> 8, g = (qq >> 4) & 15, ii = qq & 15;
    *(frag_ab*)(hout + (size_t)(b0 + b_l) * 2048 + g * 128 + ii * 8) =
        *(const frag_ab*)&xout[b_l][ii][g * 8];
  }
}

// ---------------------------------------------------------------------------
// LEGACY output gconv (fallback path).
// ---------------------------------------------------------------------------
__launch_bounds__(256, 4)
__global__ void gconv_out_kernel(const u16* __restrict__ hin,
                                 const float* __restrict__ stats_in,
                                 const float* __restrict__ gamma,
                                 const float* __restrict__ beta,
                                 const u16* __restrict__ resbuf,
                                 const short* __restrict__ Wopk,
                                 const float* __restrict__ bias,
                                 const float* __restrict__ attoff,
                                 const float* __restrict__ attd_p,
                                 float* __restrict__ out) {
  __shared__ float sc_s[128], sh_s[128];
  __shared__ float att_s[256];
  __shared__ float attd_s[16];
  __shared__ float ys[4][6][16];

  int tid = threadIdx.x;
  int wv = tid >> 6, lane = tid & 63;
  int q = lane >> 4, m = lane & 15;
  int b0 = blockIdx.x * 8;

  att_s[tid] = attoff[tid];
  if (tid < 16) attd_s[tid] = attd_p[tid];
  if (tid < 128) {
    float sum = 0.f, sq = 0.f;
#pragma unroll
    for (int s = 0; s < NSLICE; ++s) {
      sum += stats_in[s * 256 + tid];
      sq += stats_in[s * 256 + 128 + tid];
    }
    const float invN = 1.0f / (float)NROWS;
    float mu = sum * invN;
    float var = fmaxf(sq * invN - mu * mu, 0.f);
    float sc = gamma[tid] * rsqrtf(var + 1e-5f);
    sc_s[tid] = sc;
    sh_s[tid] = beta[tid] - mu * sc;
  }
  __syncthreads();

  frag_ab bfr[4];
#pragma unroll
  for (int kk = 0; kk < 4; ++kk)
    bfr[kk] = *(const frag_ab*)(Wopk + (kk * 64 + lane) * 8);

  for (int mi = 0; mi < 2; ++mi) {
    int b = b0 + wv * 2 + mi;
    size_t bb = (size_t)b * 2048;
    frag_cd acc = (frag_cd){0.f, 0.f, 0.f, 0.f};
#pragma unroll
    for (int kk = 0; kk < 4; ++kk) {
      size_t base = bb + kk * 512 + q * 128 + m * 8;
      frag_ab hv = *(const frag_ab*)(hin + base);
      frag_ab rv = *(const frag_ab*)(resbuf + base);
      const float* scp = &sc_s[kk * 32 + q * 8];
      const float* shp = &sh_s[kk * 32 + q * 8];
      frag_ab av;
#pragma unroll
      for (int e = 0; e < 8; ++e) {
        float a = fmaxf(0.f, fmaf(bf2f((unsigned short)hv[e]), scp[e], shp[e])) +
                  bf2f((unsigned short)rv[e]);
        av[e] = (short)f2bf(a);
      }
      acc = __builtin_amdgcn_mfma_f32_16x16x32_bf16(av, bfr[kk], acc, 0, 0, 0);
    }
    if (m < 6) {
#pragma unroll
      for (int r = 0; r < 4; ++r) ys[wv][m][q * 4 + r] = acc[r];
    }
    if (q < 3) {
      float v = bias[q] + attd_s[m] * ys[wv][q][m];
#pragma unroll
      for (int j = 0; j < 16; ++j) v = fmaf(att_s[m * 16 + j], ys[wv][3 + q][j], v);
      out[((size_t)b * 16 + m) * 3 + q] = v;
    }
  }
}

// ---------------------------------------------------------------------------
// Fused res-stack + out layer, v3 (low-pressure) + cg::grid.sync().
// Cooperative, grid 1024 x 256 (8 rows/block, 4 blocks/CU). h in LDS;
// residual in GLOBAL resbuf; peak arch-VGPR live ~52.
// ---------------------------------------------------------------------------
__launch_bounds__(256, 4)
__global__ void stack_fused_kernel(
    const u16* __restrict__ hbuf,       // blocked bf16 input h0 [8192][2048]
    float* __restrict__ stats,          // 9 stages x [32][256]; stage0 pre-filled
    const float* __restrict__ g0,       // layer-0 gamma
    const float* __restrict__ bt0,      // layer-0 beta
    const float* __restrict__ g_res,    // [8][128]
    const float* __restrict__ beta_res, // [8][128]
    const float* __restrict__ b_res,    // [8][128]
    const short* __restrict__ Wpk,      // [8][64][64][8]
    const short* __restrict__ attB,     // slot base; res layer k at (2+k)*512
    const short* __restrict__ Wopk_l,   // [4][64][8] this stack's out layer
    const float* __restrict__ bias_out, // [3]
    const float* __restrict__ attoff_o, // [256]
    const float* __restrict__ attd_o,   // [16]
    u16* __restrict__ resbuf,           // [8192][2048] residual (blocked bf16)
    float* __restrict__ out)            // [8192][16][3]
{
  __shared__ short Hs[16384];           // 8 batch x 2048 bf16 (32 KB)
  __shared__ float sc_s[128], sh_s[128], bias_s[128];
  __shared__ float att_s[256];
  __shared__ float attd_s[16];
  __shared__ float ys[4][6][16];

  cg::grid_group grid = cg::this_grid();

  const int tid = threadIdx.x;
  const int wv = tid >> 6, lane = tid & 63;
  const int q = lane >> 4, m = lane & 15;
  const int b0 = blockIdx.x * 8;
  const int slice = blockIdx.x & (NSLICE - 1);

  att_s[tid] = attoff_o[tid];
  if (tid < 16) attd_s[tid] = attd_o[tid];

  // preload h0 into LDS: thread's own 8 fragments, 16B/lane coalesced
#pragma unroll
  for (int b4 = 0; b4 < 2; ++b4)
#pragma unroll
    for (int kk = 0; kk < 4; ++kk) {
      int off = ((wv * 2 + b4) * 4 + kk) * 512 + lane * 8;
      *(frag_ab*)&Hs[off] = *(const frag_ab*)(hbuf + (size_t)b0 * 2048 + off);
    }

#pragma unroll 1
  for (int k = 0; k < 8; ++k) {
    if (k) grid.sync();

    // ---- phase 0: reduce BN stats stage k -> scale/shift + bias in LDS ----
    const float* st = stats + (size_t)k * (NSLICE * 256);
    const float* gg = k ? g_res + (size_t)(k - 1) * 128 : g0;
    const float* bt = k ? beta_res + (size_t)(k - 1) * 128 : bt0;
    if (tid < 128) {
      float sum = 0.f, sq = 0.f;
#pragma unroll
      for (int s = 0; s < NSLICE; ++s) {
        sum += st[s * 256 + tid];
        sq += st[s * 256 + 128 + tid];
      }
      const float invN = 1.0f / (float)NROWS;
      float mu = sum * invN;
      float var = fmaxf(sq * invN - mu * mu, 0.f);
      float sc = gg[tid] * rsqrtf(var + 1e-5f);
      sc_s[tid] = sc;
      sh_s[tid] = bt[tid] - mu * sc;
      bias_s[tid] = b_res[(size_t)k * 128 + tid];
    }
    __syncthreads();

    // ---- phase 1: in-place BN+ReLU(+res via GLOBAL resbuf) ----
    const bool doadd = (k > 0) && ((k & 1) == 0);
    const bool dosave = ((k & 1) == 0);
#pragma unroll
    for (int b4 = 0; b4 < 2; ++b4)
#pragma unroll
      for (int kk = 0; kk < 4; ++kk) {
        int off = ((wv * 2 + b4) * 4 + kk) * 512 + lane * 8;
        size_t base = (size_t)b0 * 2048 + off;
        frag_ab hv = *(const frag_ab*)&Hs[off];
        const float* scp = &sc_s[kk * 32 + q * 8];
        const float* shp = &sh_s[kk * 32 + q * 8];
        float a[8];
#pragma unroll
        for (int e = 0; e < 8; ++e)
          a[e] = fmaxf(0.f, fmaf(bf2f((unsigned short)hv[e]), scp[e], shp[e]));
        if (doadd) {
          frag_ab rv = *(const frag_ab*)(resbuf + base);
#pragma unroll
          for (int e = 0; e < 8; ++e) a[e] += bf2f((unsigned short)rv[e]);
        }
        frag_ab av;
#pragma unroll
        for (int e = 0; e < 8; ++e) av[e] = (short)f2bf(a[e]);
        *(frag_ab*)&Hs[off] = av;
        if (dosave) *(frag_ab*)(resbuf + base) = av;
      }
    __syncthreads();

    // ---- phase 2: GEMM + mix epilogue, 8 groups of 1 m-row (acc = 16) ----
    const short* Wl = Wpk + (size_t)k * 32768;
    const short* aB = attB + (size_t)(2 + k) * 512;
    frag16 bd = *(const frag16*)(aB + lane * 4);
    frag16 boff = *(const frag16*)(aB + 256 + lane * 4);

    float ssum[2][4] = {{0.f}}, ssq[2][4] = {{0.f}};
#pragma unroll 1
    for (int g = 0; g < 8; ++g) {
      frag_cd acc[4];
#pragma unroll
      for (int t = 0; t < 4; ++t) acc[t] = (frag_cd){0.f, 0.f, 0.f, 0.f};

#pragma unroll 1
      for (int kk = 0; kk < 4; ++kk) {
        frag_ab af = *(const frag_ab*)&Hs[(g * 4 + kk) * 512 + lane * 8];
#pragma unroll
        for (int t = 0; t < 4; ++t) {
          frag_ab bfr = *(const frag_ab*)(Wl + ((kk * 16 + (wv + 4 * t)) * 64 + lane) * 8);
          acc[t] = __builtin_amdgcn_mfma_f32_16x16x32_bf16(af, bfr, acc[t], 0, 0, 0);
        }
      }
      // all waves done READING row g before we overwrite it with Y
      __syncthreads();
#pragma unroll
      for (int p = 0; p < 2; ++p) {
        frag16 a0, a1;
#pragma unroll
        for (int r = 0; r < 4; ++r) {
          a0[r] = (short)f2bf(acc[p][r]);
          a1[r] = (short)f2bf(acc[p + 2][r]);
        }
        frag_cd d = (frag_cd){0.f, 0.f, 0.f, 0.f};
        d = __builtin_amdgcn_mfma_f32_16x16x16bf16_1k(a0, bd, d, 0, 0, 0);
        d = __builtin_amdgcn_mfma_f32_16x16x16bf16_1k(a1, boff, d, 0, 0, 0);
        int colbase = (p == 0) ? wv * 16 : 64 + wv * 16;
        frag16 sv;
#pragma unroll
        for (int r = 0; r < 4; ++r) {
          float v = d[r] + bias_s[colbase + q * 4 + r];
          ssum[p][r] += v;
          ssq[p][r] = fmaf(v, v, ssq[p][r]);
          sv[r] = (short)f2bf(v);
        }
        *(frag16*)&Hs[g * 2048 + (colbase / 8 + (q >> 1)) * 128 + m * 8 + (q & 1) * 4] = sv;
      }
      // no barrier after: group g+1 reads row g+1, disjoint from these writes
    }

    // ---- phase 3: BN stats -> stage k+1 (device-scope atomics @ LLC) ----
    float* so = stats + (size_t)(k + 1) * (NSLICE * 256);
#pragma unroll
    for (int p = 0; p < 2; ++p)
#pragma unroll
      for (int r = 0; r < 4; ++r) {
        float v1 = ssum[p][r], v2 = ssq[p][r];
        v1 += __shfl_xor(v1, 1); v2 += __shfl_xor(v2, 1);
        v1 += __shfl_xor(v1, 2); v2 += __shfl_xor(v2, 2);
        v1 += __shfl_xor(v1, 4); v2 += __shfl_xor(v2, 4);
        v1 += __shfl_xor(v1, 8); v2 += __shfl_xor(v2, 8);
        if (m == 0) {
          int c = ((p == 0) ? wv * 16 : 64 + wv * 16) + q * 4 + r;
          atomicAdd(&so[slice * 256 + c], v1);
          atomicAdd(&so[slice * 256 + 128 + c], v2);
        }
      }
  }

  // ---- out stage: BN + residual (from resbuf) + Fout=3 gconv ----
  grid.sync();
  {
    const float* st = stats + (size_t)8 * (NSLICE * 256);
    if (tid < 128) {
      float sum = 0.f, sq = 0.f;
#pragma unroll
      for (int s = 0; s < NSLICE; ++s) {
        sum += st[s * 256 + tid];
        sq += st[s * 256 + 128 + tid];
      }
      const float invN = 1.0f / (float)NROWS;
      float mu = sum * invN;
      float var = fmaxf(sq * invN - mu * mu, 0.f);
      float sc = g_res[7 * 128 + tid] * rsqrtf(var + 1e-5f);
      sc_s[tid] = sc;
      sh_s[tid] = beta_res[7 * 128 + tid] - mu * sc;
    }
    __syncthreads();

    for (int b4 = 0; b4 < 2; ++b4) {
      int bl = wv * 2 + b4;
      int b = b0 + bl;
      frag_cd acc = (frag_cd){0.f, 0.f, 0.f, 0.f};
#pragma unroll
      for (int kk = 0; kk < 4; ++kk) {
        int off = (bl * 4 + kk) * 512 + lane * 8;
        size_t base = (size_t)b0 * 2048 + off;
        frag_ab hv = *(const frag_ab*)&Hs[off];
        frag_ab rv = *(const frag_ab*)(resbuf + base);
        frag_ab bfrO = *(const frag_ab*)(Wopk_l + (kk * 64 + lane) * 8);
        const float* scp = &sc_s[kk * 32 + q * 8];
        const float* shp = &sh_s[kk * 32 + q * 8];
        frag_ab av;
#pragma unroll
        for (int e = 0; e < 8; ++e) {
          float a = fmaxf(0.f, fmaf(bf2f((unsigned short)hv[e]), scp[e], shp[e])) +
                    bf2f((unsigned short)rv[e]);
          av[e] = (short)f2bf(a);
        }
        acc = __builtin_amdgcn_mfma_f32_16x16x32_bf16(av, bfrO, acc, 0, 0, 0);
      }
      if (m < 6) {
#pragma unroll
        for (int r = 0; r < 4; ++r) ys[wv][m][q * 4 + r] = acc[r];
      }
      // same-wave LDS ops are in-order; no barrier needed (proven pattern)
      if (q < 3) {
        float v = bias_out[q] + attd_s[m] * ys[wv][q][m];
#pragma unroll
        for (int j = 0; j < 16; ++j) v = fmaf(att_s[m * 16 + j], ys[wv][3 + q][j], v);
        out[((size_t)b * 16 + m) * 3 + q] = v;
      }
    }
  }
}

// merged[b,j,c] = out_{1+c/3}[b,j,c%3]; out_i at d_out + i*393216
__global__ void pack_merged(const float* __restrict__ dout, float* __restrict__ merged) {
  int idx = blockIdx.x * 256 + threadIdx.x;
  if (idx >= BATCH * NJ * 12) return;
  int c = idx % 12;
  int bj = idx / 12;
  merged[idx] = dout[(size_t)(1 + c / 3) * 393216 + (size_t)bj * 3 + (c % 3)];
}

extern "C" void kernel_launch(void* const* d_in, const int* in_sizes, int n_in,
                              void* d_out, int out_size, void* d_ws, size_t ws_size,
                              hipStream_t stream) {
  (void)in_sizes; (void)n_in; (void)out_size; (void)ws_size;
  const float* W_in = (const float*)d_in[4];
  const float* b_in = (const float*)d_in[5];
  const float* e_in = (const float*)d_in[6];
  const float* g_in = (const float*)d_in[7];
  const float* beta_in = (const float*)d_in[8];
  const float* W_cat = (const float*)d_in[9];
  const float* b_cat = (const float*)d_in[10];
  const float* e_cat = (const float*)d_in[11];
  const float* g_cat = (const float*)d_in[12];
  const float* beta_cat = (const float*)d_in[13];
  const float* W_res = (const float*)d_in[14];
  const float* b_res = (const float*)d_in[15];
  const float* e_res = (const float*)d_in[16];
  const float* g_res = (const float*)d_in[17];
  const float* beta_res = (const float*)d_in[18];
  const float* W_out = (const float*)d_in[19];
  const float* b_out = (const float*)d_in[20];
  const float* e_out = (const float*)d_in[21];

  float* ws = (float*)d_ws;
  float* att_off = ws;                          // 3840 fl
  float* attd = att_off + 3840;                 // 240 fl (pad to 256)
  short* attB = (short*)(attd + 256);           // 15*512 shorts
  short* Wpk = attB + 15 * 512;                 // 8*64*512 = 262144 shorts
  short* Wopk = Wpk + 262144;                   // 5*2048 = 10240 shorts
  float* stats = (float*)(Wopk + 10240);        // 45 slots x 32 x 256 fl
  float* merged = stats + 45 * NSLICE * 256;    // B*16*12 fl
  u16* hbuf = (u16*)(merged + (size_t)BATCH * NJ * 12);  // 16777216 u16
  u16* Rg = hbuf + (size_t)BATCH * NJ * FHID;            // resbuf

  hipMemsetAsync(stats, 0, 45 * NSLICE * 256 * sizeof(float), stream);
  att_kernel<<<1, 256, 0, stream>>>(e_in, e_cat, e_res, e_out, att_off, attd);
  pack_attB<<<4, 256, 0, stream>>>(att_off, attd, attB);
  pack_w_kernel<<<128, 256, 0, stream>>>(W_res, Wpk);
  pack_wout<<<5, 256, 0, stream>>>(W_out, Wopk);

  float* dout = (float*)d_out;
  const int SSTRIDE = NSLICE * 256;

  int coop = 0, dev = 0;
  hipGetDevice(&dev);
  hipDeviceGetAttribute(&coop, hipDeviceAttributeCooperativeLaunch, dev);

  // GUARD: only use the fused kernel if it compiled spill-free.
  hipFuncAttributes fa;
  bool fused_ok = (coop != 0) &&
                  (hipFuncGetAttributes(&fa, (const void*)stack_fused_kernel) == hipSuccess) &&
                  (fa.localSizeBytes == 0);

  auto run_stack_legacy = [&](int sb, const float* g0, const float* bt0, int out_layer,
                              const float* bo, int att_out_slot, float* optr) {
    for (int k = 0; k < 8; ++k) {
      const float* gg = (k == 0) ? g0 : g_res + (size_t)(k - 1) * FHID;
      const float* bb = (k == 0) ? bt0 : beta_res + (size_t)(k - 1) * FHID;
      int rm = (k == 0) ? 2 : ((k % 2 == 0) ? 3 : 0);
      gconv_mfma_kernel<<<BATCH / 8, 256, 0, stream>>>(
          hbuf, stats + (size_t)(sb + k) * SSTRIDE, gg, bb, Rg, rm,
          Wpk + (size_t)k * 32768, b_res + (size_t)k * FHID,
          attB + (size_t)(2 + k) * 512, hbuf,
          stats + (size_t)(sb + k + 1) * SSTRIDE);
    }
    gconv_out_kernel<<<BATCH / 8, 256, 0, stream>>>(
        hbuf, stats + (size_t)(sb + 8) * SSTRIDE, g_res + 7 * FHID,
        beta_res + 7 * FHID, Rg, Wopk + (size_t)out_layer * 2048, bo,
        att_off + (size_t)att_out_slot * 256, attd + (size_t)att_out_slot * 16,
        optr);
  };

  auto run_fused = [&](const float* g0p, const float* bt0p, int out_layer,
                       const float* bo, int slot, float* optr, float* st) -> bool {
    if (!fused_ok) return false;
    const u16* a0 = hbuf;
    float* a1 = st;
    const float* a2 = g0p;
    const float* a3 = bt0p;
    const float* a4 = g_res;
    const float* a5 = beta_res;
    const float* a6 = b_res;
    const short* a7 = Wpk;
    const short* a8 = attB;
    const short* a9 = Wopk + (size_t)out_layer * 2048;
    const float* a10 = bo;
    const float* a11 = att_off + (size_t)slot * 256;
    const float* a12 = attd + (size_t)slot * 16;
    u16* a13 = Rg;
    float* a14 = optr;
    void* args[15] = {&a0, &a1, &a2, &a3, &a4, &a5, &a6, &a7,
                      &a8, &a9, &a10, &a11, &a12, &a13, &a14};
    return hipLaunchCooperativeKernel((const void*)stack_fused_kernel, dim3(1024),
                                      dim3(256), args, 0, stream) == hipSuccess;
  };

  for (int bi = 0; bi < 4; ++bi) {
    gconv_kernel<2><<<BATCH / 2, 256, 0, stream>>>(
        (const float*)d_in[bi], W_in, b_in, att_off, attd, hbuf,
        stats + (size_t)(bi * 9) * SSTRIDE);
    if (!run_fused(g_in, beta_in, bi, b_out + bi * 3, 10 + bi,
                   dout + (size_t)(1 + bi) * 393216,
                   stats + (size_t)(bi * 9) * SSTRIDE))
      run_stack_legacy(bi * 9, g_in, beta_in, bi, b_out + bi * 3, 10 + bi,
                       dout + (size_t)(1 + bi) * 393216);
  }

  pack_merged<<<(BATCH * NJ * 12 + 255) / 256, 256, 0, stream>>>(dout, merged);
  gconv_kernel<12><<<BATCH / 2, 256, 0, stream>>>(
      merged, W_cat, b_cat, att_off + 256, attd + 16, hbuf,
      stats + (size_t)36 * SSTRIDE);
  if (!run_fused(g_cat, beta_cat, 4, b_out + 12, 14, dout,
                 stats + (size_t)36 * SSTRIDE))
    run_stack_legacy(36, g_cat, beta_cat, 4, b_out + 12, 14, dout);
}

// Round 7
// 1771.684 us; speedup vs baseline: 2.4925x; 1.0124x over previous
//
#include <hip/hip_runtime.h>
#include <hip/hip_bf16.h>
#include <hip/hip_cooperative_groups.h>

namespace cg = cooperative_groups;

// ---------------------------------------------------------------------------
// SemGCN forward, round 10.
//  * Single fused res-stack variant, geometry chosen so residency is
//    guaranteed by LDS, not by the register allocator:
//      - 16 batch rows/block, grid 512, Hs = 64KB -> 2 blocks/CU (LDS-bound).
//      - launch_bounds(256,2) -> >=2 blocks/CU guaranteed -> grid 512 always
//        co-resident; cooperative launch cannot fail residency validation.
//      - low-pressure body (residual in GLOBAL resbuf, acc[4]=16 AGPR,
//        16 m-row groups): total live ~80-100 regs incl. AGPR.
//  * Launch is PRE-VALIDATED on host (occupancy >= 2 and localSizeBytes <= 64)
//    -- round 6's failure mode was plausibly a failed cooperative launch
//    poisoning graph capture; we never attempt a launch that could fail.
//  * cg::grid.sync() (clean in rounds 1/5); no homemade spin barrier.
// ---------------------------------------------------------------------------

#define BATCH 8192
#define NJ 16
#define FHID 128
#define NROWS (BATCH * NJ)   // 131072
#define NSLICE 32

typedef unsigned short u16;
typedef __attribute__((ext_vector_type(8))) short frag_ab;  // 8 bf16
typedef __attribute__((ext_vector_type(4))) short frag16;   // 4 bf16
typedef __attribute__((ext_vector_type(4))) float frag_cd;  // 4 fp32

__device__ __forceinline__ unsigned short f2bf(float f) {
  unsigned u = __float_as_uint(f);
  u = u + 0x7FFF + ((u >> 16) & 1);  // RNE
  return (unsigned short)(u >> 16);
}
__device__ __forceinline__ float bf2f(unsigned short s) {
  return __uint_as_float((unsigned)s << 16);
}

// H36M 16-joint adjacency + diag, row bitmasks (bit j set if mask[i][j])
__constant__ unsigned short kMaskBits[16] = {
    0x0093, 0x0007, 0x000E, 0x000C, 0x0031, 0x0070, 0x0060, 0x0181,
    0x4B80, 0x0700, 0x0600, 0x1900, 0x3800, 0x3000, 0xC100, 0xC000};

// 15 att slots: 0=in, 1=cat, 2..9=res[0..7], 10..14=out[0..4]
__global__ void att_kernel(const float* __restrict__ e_in,
                           const float* __restrict__ e_cat,
                           const float* __restrict__ e_res,
                           const float* __restrict__ e_out,
                           float* __restrict__ att_off,
                           float* __restrict__ attd) {
  int t = threadIdx.x;
  if (t >= 240) return;
  int m = t >> 4, i = t & 15;
  const float* e;
  if (m == 0) e = e_in;
  else if (m == 1) e = e_cat;
  else if (m < 10) e = e_res + (m - 2) * 256;
  else e = e_out + (m - 10) * 256;
  unsigned msk = kMaskBits[i];
  float mx = -3.0e38f;
  for (int j = 0; j < 16; ++j)
    if ((msk >> j) & 1) mx = fmaxf(mx, e[i * 16 + j]);
  float v[16];
  float s = 0.0f;
  for (int j = 0; j < 16; ++j) {
    float val = ((msk >> j) & 1) ? expf(e[i * 16 + j] - mx) : 0.0f;
    v[j] = val;
    s += val;
  }
  float inv = 1.0f / s;
  for (int j = 0; j < 16; ++j)
    att_off[m * 256 + i * 16 + j] = (j == i) ? 0.0f : v[j] * inv;
  attd[m * 16 + i] = v[i] * inv;
}

// att -> bf16 B-fragments for mfma_16x16x16: B[k=(l>>4)*4+j][n=l&15].
__global__ void pack_attB(const float* __restrict__ att_off,
                          const float* __restrict__ attd,
                          short* __restrict__ attB) {
  int idx = blockIdx.x * 256 + threadIdx.x;
  if (idx >= 15 * 64) return;
  int slot = idx >> 6, lane = idx & 63;
  int n = lane & 15, q = lane >> 4;
  frag16 bd, bo;
#pragma unroll
  for (int j = 0; j < 4; ++j) {
    int k = q * 4 + j;
    bd[j] = (short)f2bf(k == n ? attd[slot * 16 + n] : 0.0f);
    bo[j] = (short)f2bf(att_off[slot * 256 + n * 16 + k]);  // attoff^T[k][n]
  }
  *(frag16*)(attB + slot * 512 + lane * 4) = bd;
  *(frag16*)(attB + slot * 512 + 256 + lane * 4) = bo;
}

// W_res[8][2][128][128] fp32 -> bf16 B-fragments (16x16x32).
__global__ void pack_w_kernel(const float* __restrict__ W_res,
                              short* __restrict__ Wpk) {
  int idx = blockIdx.x * 256 + threadIdx.x;  // 8*64*64 = 32768
  int lane = idx & 63;
  int frag = (idx >> 6) & 63;  // kk*16+nt
  int layer = idx >> 12;
  int kk = frag >> 4, nt = frag & 15;
  int n = nt * 16 + (lane & 15);
  int kbase = kk * 32 + (lane >> 4) * 8;
  int mat = n >> 7, c = n & 127;
  const float* Wsrc = W_res + (((size_t)layer * 2 + mat) * 128) * 128;
  short* dst = Wpk + ((size_t)(layer * 64 + frag)) * 512 + lane * 8;
#pragma unroll
  for (int j = 0; j < 8; ++j)
    dst[j] = (short)f2bf(Wsrc[(size_t)(kbase + j) * 128 + c]);
}

// W_out[5][2][128][3] -> bf16 B-frags, N=16: cols 0-2 = W0, 3-5 = W1, rest 0.
__global__ void pack_wout(const float* __restrict__ W_out,
                          short* __restrict__ Wopk) {
  int idx = blockIdx.x * 256 + threadIdx.x;  // 5*4*64 = 1280
  if (idx >= 1280) return;
  int layer = idx >> 8, rem = idx & 255;
  int kk = rem >> 6, lane = rem & 63;
  int n = lane & 15, q = lane >> 4;
  frag_ab v;
#pragma unroll
  for (int j = 0; j < 8; ++j) {
    int k = kk * 32 + q * 8 + j;
    float val = 0.0f;
    if (n < 3) val = W_out[((size_t)(layer * 2 + 0) * 128 + k) * 3 + n];
    else if (n < 6) val = W_out[((size_t)(layer * 2 + 1) * 128 + k) * 3 + (n - 3)];
    v[j] = (short)f2bf(val);
  }
  *(frag_ab*)(Wopk + ((size_t)(layer * 4 + kk) * 64 + lane) * 8) = v;
}

// ---------------------------------------------------------------------------
// LEGACY heavy layer (fallback path).
// ---------------------------------------------------------------------------
__launch_bounds__(256, 3)
__global__ void gconv_mfma_kernel(const u16* __restrict__ hin,
                                  const float* __restrict__ stats_in,
                                  const float* __restrict__ gamma,
                                  const float* __restrict__ beta,
                                  u16* __restrict__ resbuf,
                                  int res_mode,
                                  const short* __restrict__ Wpk,
                                  const float* __restrict__ bias,
                                  const short* __restrict__ attB,
                                  u16* __restrict__ hout,
                                  float* __restrict__ stats_out) {
  __shared__ short Apk[32 * 512];
  __shared__ float sc_s[128], sh_s[128];

  int tid = threadIdx.x;
  int wv = tid >> 6, lane = tid & 63;
  int q = lane >> 4, m = lane & 15;
  int b0 = blockIdx.x * 8;
  int slice = blockIdx.x & (NSLICE - 1);

  frag16 bd = *(const frag16*)(attB + lane * 4);
  frag16 boff = *(const frag16*)(attB + 256 + lane * 4);
  float biasr[2][4];
  *(float4*)biasr[0] = *(const float4*)(bias + wv * 16 + q * 4);
  *(float4*)biasr[1] = *(const float4*)(bias + 64 + wv * 16 + q * 4);

  if (tid < 128) {
    float sum = 0.f, sq = 0.f;
#pragma unroll
    for (int s = 0; s < NSLICE; ++s) {
      sum += stats_in[s * 256 + tid];
      sq += stats_in[s * 256 + 128 + tid];
    }
    const float invN = 1.0f / (float)NROWS;
    float mu = sum * invN;
    float var = fmaxf(sq * invN - mu * mu, 0.f);
    float sc = gamma[tid] * rsqrtf(var + 1e-5f);
    sc_s[tid] = sc;
    sh_s[tid] = beta[tid] - mu * sc;
  }
  __syncthreads();

#pragma unroll
  for (int mi = 0; mi < 2; ++mi) {
    int mt = wv * 2 + mi;
    size_t bb = (size_t)(b0 + mt) * 2048;
#pragma unroll
    for (int kk = 0; kk < 4; ++kk) {
      size_t base = bb + kk * 512 + q * 128 + m * 8;
      frag_ab hv = *(const frag_ab*)(hin + base);
      const float* scp = &sc_s[kk * 32 + q * 8];
      const float* shp = &sh_s[kk * 32 + q * 8];
      float a[8];
#pragma unroll
      for (int e = 0; e < 8; ++e)
        a[e] = fmaxf(0.f, fmaf(bf2f((unsigned short)hv[e]), scp[e], shp[e]));
      if (res_mode & 1) {
        frag_ab rv = *(const frag_ab*)(resbuf + base);
#pragma unroll
        for (int e = 0; e < 8; ++e) a[e] += bf2f((unsigned short)rv[e]);
      }
      frag_ab av;
#pragma unroll
      for (int e = 0; e < 8; ++e) av[e] = (short)f2bf(a[e]);
      *(frag_ab*)&Apk[(mt * 4 + kk) * 512 + lane * 8] = av;
      if (res_mode & 2) *(frag_ab*)(resbuf + base) = av;
    }
  }
  __syncthreads();

  float ssum[2][4] = {{0.f}}, ssq[2][4] = {{0.f}};
  for (int half = 0; half < 2; ++half) {
    frag_cd acc[4][4];
#pragma unroll
    for (int mi = 0; mi < 4; ++mi)
#pragma unroll
      for (int t = 0; t < 4; ++t) acc[mi][t] = (frag_cd){0.f, 0.f, 0.f, 0.f};

#pragma unroll
    for (int kk = 0; kk < 4; ++kk) {
      frag_ab bfr[4];
#pragma unroll
      for (int t = 0; t < 4; ++t) {
        int nt = wv + 4 * t;
        bfr[t] = *(const frag_ab*)(Wpk + ((kk * 16 + nt) * 64 + lane) * 8);
      }
#pragma unroll
      for (int mi = 0; mi < 4; ++mi) {
        frag_ab af = *(const frag_ab*)&Apk[((half * 4 + mi) * 4 + kk) * 512 + lane * 8];
#pragma unroll
        for (int t = 0; t < 4; ++t)
          acc[mi][t] = __builtin_amdgcn_mfma_f32_16x16x32_bf16(af, bfr[t],
                                                               acc[mi][t], 0, 0, 0);
      }
    }

#pragma unroll
    for (int mi = 0; mi < 4; ++mi) {
      size_t bb = (size_t)(b0 + half * 4 + mi) * 2048;
#pragma unroll
      for (int p = 0; p < 2; ++p) {
        frag16 a0, a1;
#pragma unroll
        for (int r = 0; r < 4; ++r) {
          a0[r] = (short)f2bf(acc[mi][p][r]);
          a1[r] = (short)f2bf(acc[mi][p + 2][r]);
        }
        frag_cd d = (frag_cd){0.f, 0.f, 0.f, 0.f};
        d = __builtin_amdgcn_mfma_f32_16x16x16bf16_1k(a0, bd, d, 0, 0, 0);
        d = __builtin_amdgcn_mfma_f32_16x16x16bf16_1k(a1, boff, d, 0, 0, 0);
        int colbase = (p == 0) ? wv * 16 : 64 + wv * 16;
        frag16 sv;
#pragma unroll
        for (int r = 0; r < 4; ++r) {
          float v = d[r] + biasr[p][r];
          ssum[p][r] += v;
          ssq[p][r] = fmaf(v, v, ssq[p][r]);
          sv[r] = (short)f2bf(v);
        }
        size_t addr = bb + (size_t)(colbase / 8 + (q >> 1)) * 128 + m * 8 + (q & 1) * 4;
        *(frag16*)(hout + addr) = sv;
      }
    }
  }

#pragma unroll
  for (int p = 0; p < 2; ++p)
#pragma unroll
    for (int r = 0; r < 4; ++r) {
      float v1 = ssum[p][r], v2 = ssq[p][r];
      v1 += __shfl_xor(v1, 1); v2 += __shfl_xor(v2, 1);
      v1 += __shfl_xor(v1, 2); v2 += __shfl_xor(v2, 2);
      v1 += __shfl_xor(v1, 4); v2 += __shfl_xor(v2, 4);
      v1 += __shfl_xor(v1, 8); v2 += __shfl_xor(v2, 8);
      if (m == 0) {
        int c = ((p == 0) ? wv * 16 : 64 + wv * 16) + q * 4 + r;
        atomicAdd(&stats_out[slice * 256 + c], v1);
        atomicAdd(&stats_out[slice * 256 + 128 + c], v2);
      }
    }
}

// ---------------------------------------------------------------------------
// Small-K layers (Fin=2, Fin=12): fp32 VALU, blocked bf16 output via LDS.
// ---------------------------------------------------------------------------
template <int FIN>
__launch_bounds__(256)
__global__ void gconv_kernel(const float* __restrict__ hin,
                             const float* __restrict__ W,
                             const float* __restrict__ bias,
                             const float* __restrict__ attoff,
                             const float* __restrict__ attd_p,
                             u16* __restrict__ hout,
                             float* __restrict__ stats_out) {
  __shared__ float xin[2][NJ][FIN];
  __shared__ float att_s[256];
  __shared__ float attd_s[16];
  __shared__ float red[256];
  __shared__ short xout[2][NJ][128];

  int tid = threadIdx.x;
  int b0 = blockIdx.x * 2;
  int slice = blockIdx.x & (NSLICE - 1);

  att_s[tid] = attoff[tid];
  if (tid < 16) attd_s[tid] = attd_p[tid];

  const int TOT4 = 2 * NJ * FIN / 4;
  const float4* hin4 = (const float4*)(hin + (size_t)b0 * NJ * FIN);
  for (int k = tid; k < TOT4; k += 256)
    ((float4*)&xin[0][0][0])[k] = hin4[k];
  __syncthreads();

  int o = tid & 127;
  int bl = tid >> 7;
  float acc0[16], acc1[16];
#pragma unroll
  for (int j = 0; j < 16; ++j) { acc0[j] = 0.0f; acc1[j] = 0.0f; }
  const float* W0 = W;
  const float* W1 = W + FIN * FHID;
  if constexpr (FIN % 4 == 0) {
    for (int f = 0; f < FIN; f += 4) {
      float w00 = W0[(f + 0) * FHID + o], w01 = W0[(f + 1) * FHID + o];
      float w02 = W0[(f + 2) * FHID + o], w03 = W0[(f + 3) * FHID + o];
      float w10 = W1[(f + 0) * FHID + o], w11 = W1[(f + 1) * FHID + o];
      float w12 = W1[(f + 2) * FHID + o], w13 = W1[(f + 3) * FHID + o];
#pragma unroll
      for (int j = 0; j < 16; ++j) {
        float4 xv = *(const float4*)&xin[bl][j][f];
        acc0[j] = fmaf(xv.x, w00, fmaf(xv.y, w01, fmaf(xv.z, w02, fmaf(xv.w, w03, acc0[j]))));
        acc1[j] = fmaf(xv.x, w10, fmaf(xv.y, w11, fmaf(xv.z, w12, fmaf(xv.w, w13, acc1[j]))));
      }
    }
  } else {
    for (int f = 0; f < FIN; ++f) {
      float w0 = W0[f * FHID + o], w1 = W1[f * FHID + o];
#pragma unroll
      for (int j = 0; j < 16; ++j) {
        float xv = xin[bl][j][f];
        acc0[j] = fmaf(xv, w0, acc0[j]);
        acc1[j] = fmaf(xv, w1, acc1[j]);
      }
    }
  }

  float bo = bias[o];
  float ssum = 0.0f, ssq = 0.0f;
#pragma unroll
  for (int i = 0; i < 16; ++i) {
    float h = fmaf(attd_s[i], acc0[i], bo);
#pragma unroll
    for (int j = 0; j < 16; ++j) h = fmaf(att_s[i * 16 + j], acc1[j], h);
    xout[bl][i][o] = (short)f2bf(h);
    ssum += h;
    ssq = fmaf(h, h, ssq);
  }
  __syncthreads();
  red[tid] = ssum;
  __syncthreads();
  if (bl == 0) atomicAdd(&stats_out[slice * 256 + o], ssum + red[o + 128]);
  __syncthreads();
  red[tid] = ssq;
  __syncthreads();
  if (bl == 0) atomicAdd(&stats_out[slice * 256 + 128 + o], ssq + red[o + 128]);
  __syncthreads();

  for (int qq = tid; qq < 512; qq += 256) {
    int b_l = qq >> 8, g = (qq >> 4) & 15, ii = qq & 15;
    *(frag_ab*)(hout + (size_t)(b0 + b_l) * 2048 + g * 128 + ii * 8) =
        *(const frag_ab*)&xout[b_l][ii][g * 8];
  }
}

// ---------------------------------------------------------------------------
// LEGACY output gconv (fallback path).
// ---------------------------------------------------------------------------
__launch_bounds__(256, 4)
__global__ void gconv_out_kernel(const u16* __restrict__ hin,
                                 const float* __restrict__ stats_in,
                                 const float* __restrict__ gamma,
                                 const float* __restrict__ beta,
                                 const u16* __restrict__ resbuf,
                                 const short* __restrict__ Wopk,
                                 const float* __restrict__ bias,
                                 const float* __restrict__ attoff,
                                 const float* __restrict__ attd_p,
                                 float* __restrict__ out) {
  __shared__ float sc_s[128], sh_s[128];
  __shared__ float att_s[256];
  __shared__ float attd_s[16];
  __shared__ float ys[4][6][16];

  int tid = threadIdx.x;
  int wv = tid >> 6, lane = tid & 63;
  int q = lane >> 4, m = lane & 15;
  int b0 = blockIdx.x * 8;

  att_s[tid] = attoff[tid];
  if (tid < 16) attd_s[tid] = attd_p[tid];
  if (tid < 128) {
    float sum = 0.f, sq = 0.f;
#pragma unroll
    for (int s = 0; s < NSLICE; ++s) {
      sum += stats_in[s * 256 + tid];
      sq += stats_in[s * 256 + 128 + tid];
    }
    const float invN = 1.0f / (float)NROWS;
    float mu = sum * invN;
    float var = fmaxf(sq * invN - mu * mu, 0.f);
    float sc = gamma[tid] * rsqrtf(var + 1e-5f);
    sc_s[tid] = sc;
    sh_s[tid] = beta[tid] - mu * sc;
  }
  __syncthreads();

  frag_ab bfr[4];
#pragma unroll
  for (int kk = 0; kk < 4; ++kk)
    bfr[kk] = *(const frag_ab*)(Wopk + (kk * 64 + lane) * 8);

  for (int mi = 0; mi < 2; ++mi) {
    int b = b0 + wv * 2 + mi;
    size_t bb = (size_t)b * 2048;
    frag_cd acc = (frag_cd){0.f, 0.f, 0.f, 0.f};
#pragma unroll
    for (int kk = 0; kk < 4; ++kk) {
      size_t base = bb + kk * 512 + q * 128 + m * 8;
      frag_ab hv = *(const frag_ab*)(hin + base);
      frag_ab rv = *(const frag_ab*)(resbuf + base);
      const float* scp = &sc_s[kk * 32 + q * 8];
      const float* shp = &sh_s[kk * 32 + q * 8];
      frag_ab av;
#pragma unroll
      for (int e = 0; e < 8; ++e) {
        float a = fmaxf(0.f, fmaf(bf2f((unsigned short)hv[e]), scp[e], shp[e])) +
                  bf2f((unsigned short)rv[e]);
        av[e] = (short)f2bf(a);
      }
      acc = __builtin_amdgcn_mfma_f32_16x16x32_bf16(av, bfr[kk], acc, 0, 0, 0);
    }
    if (m < 6) {
#pragma unroll
      for (int r = 0; r < 4; ++r) ys[wv][m][q * 4 + r] = acc[r];
    }
    if (q < 3) {
      float v = bias[q] + attd_s[m] * ys[wv][q][m];
#pragma unroll
      for (int j = 0; j < 16; ++j) v = fmaf(att_s[m * 16 + j], ys[wv][3 + q][j], v);
      out[((size_t)b * 16 + m) * 3 + q] = v;
    }
  }
}

// ---------------------------------------------------------------------------
// Fused res-stack + out layer. 16 rows/block, grid 512, LDS-bound 2 blocks/CU.
// Low-pressure: residual in GLOBAL resbuf, acc[4]=16 AGPR, 16 m-row groups.
// ---------------------------------------------------------------------------
__launch_bounds__(256, 2)
__global__ void stack_fused_kernel(
    const u16* __restrict__ hbuf,       // blocked bf16 input h0 [8192][2048]
    float* __restrict__ stats,          // 9 stages x [32][256]; stage0 pre-filled
    const float* __restrict__ g0,       // layer-0 gamma
    const float* __restrict__ bt0,      // layer-0 beta
    const float* __restrict__ g_res,    // [8][128]
    const float* __restrict__ beta_res, // [8][128]
    const float* __restrict__ b_res,    // [8][128]
    const short* __restrict__ Wpk,      // [8][64][64][8]
    const short* __restrict__ attB,     // slot base; res layer k at (2+k)*512
    const short* __restrict__ Wopk_l,   // [4][64][8] this stack's out layer
    const float* __restrict__ bias_out, // [3]
    const float* __restrict__ attoff_o, // [256]
    const float* __restrict__ attd_o,   // [16]
    u16* __restrict__ resbuf,           // [8192][2048] residual (blocked bf16)
    float* __restrict__ out)            // [8192][16][3]
{
  __shared__ short Hs[32768];           // 16 batch x 2048 bf16 (64 KB)
  __shared__ float sc_s[128], sh_s[128], bias_s[128];
  __shared__ float att_s[256];
  __shared__ float attd_s[16];
  __shared__ float ys[4][6][16];

  cg::grid_group grid = cg::this_grid();

  const int tid = threadIdx.x;
  const int wv = tid >> 6, lane = tid & 63;
  const int q = lane >> 4, m = lane & 15;
  const int b0 = blockIdx.x * 16;
  const int slice = blockIdx.x & (NSLICE - 1);

  att_s[tid] = attoff_o[tid];
  if (tid < 16) attd_s[tid] = attd_o[tid];

  // preload h0 into LDS: thread's own 16 fragments, 16B/lane coalesced
#pragma unroll
  for (int b4 = 0; b4 < 4; ++b4)
#pragma unroll
    for (int kk = 0; kk < 4; ++kk) {
      int off = ((wv * 4 + b4) * 4 + kk) * 512 + lane * 8;
      *(frag_ab*)&Hs[off] = *(const frag_ab*)(hbuf + (size_t)b0 * 2048 + off);
    }

#pragma unroll 1
  for (int k = 0; k < 8; ++k) {
    if (k) grid.sync();

    // ---- phase 0: reduce BN stats stage k -> scale/shift + bias in LDS ----
    const float* st = stats + (size_t)k * (NSLICE * 256);
    const float* gg = k ? g_res + (size_t)(k - 1) * 128 : g0;
    const float* bt = k ? beta_res + (size_t)(k - 1) * 128 : bt0;
    if (tid < 128) {
      float sum = 0.f, sq = 0.f;
#pragma unroll
      for (int s = 0; s < NSLICE; ++s) {
        sum += st[s * 256 + tid];
        sq += st[s * 256 + 128 + tid];
      }
      const float invN = 1.0f / (float)NROWS;
      float mu = sum * invN;
      float var = fmaxf(sq * invN - mu * mu, 0.f);
      float sc = gg[tid] * rsqrtf(var + 1e-5f);
      sc_s[tid] = sc;
      sh_s[tid] = bt[tid] - mu * sc;
      bias_s[tid] = b_res[(size_t)k * 128 + tid];
    }
    __syncthreads();

    // ---- phase 1: in-place BN+ReLU(+res via GLOBAL resbuf) ----
    const bool doadd = (k > 0) && ((k & 1) == 0);
    const bool dosave = ((k & 1) == 0);
#pragma unroll
    for (int b4 = 0; b4 < 4; ++b4)
#pragma unroll
      for (int kk = 0; kk < 4; ++kk) {
        int off = ((wv * 4 + b4) * 4 + kk) * 512 + lane * 8;
        size_t base = (size_t)b0 * 2048 + off;
        frag_ab hv = *(const frag_ab*)&Hs[off];
        const float* scp = &sc_s[kk * 32 + q * 8];
        const float* shp = &sh_s[kk * 32 + q * 8];
        float a[8];
#pragma unroll
        for (int e = 0; e < 8; ++e)
          a[e] = fmaxf(0.f, fmaf(bf2f((unsigned short)hv[e]), scp[e], shp[e]));
        if (doadd) {
          frag_ab rv = *(const frag_ab*)(resbuf + base);
#pragma unroll
          for (int e = 0; e < 8; ++e) a[e] += bf2f((unsigned short)rv[e]);
        }
        frag_ab av;
#pragma unroll
        for (int e = 0; e < 8; ++e) av[e] = (short)f2bf(a[e]);
        *(frag_ab*)&Hs[off] = av;
        if (dosave) *(frag_ab*)(resbuf + base) = av;
      }
    __syncthreads();

    // ---- phase 2: GEMM + mix epilogue, 16 groups of 1 m-row (acc = 16) ----
    const short* Wl = Wpk + (size_t)k * 32768;
    const short* aB = attB + (size_t)(2 + k) * 512;
    frag16 bd = *(const frag16*)(aB + lane * 4);
    frag16 boff = *(const frag16*)(aB + 256 + lane * 4);

    float ssum[2][4] = {{0.f}}, ssq[2][4] = {{0.f}};
#pragma unroll 1
    for (int g = 0; g < 16; ++g) {
      frag_cd acc[4];
#pragma unroll
      for (int t = 0; t < 4; ++t) acc[t] = (frag_cd){0.f, 0.f, 0.f, 0.f};

#pragma unroll 1
      for (int kk = 0; kk < 4; ++kk) {
        frag_ab af = *(const frag_ab*)&Hs[(g * 4 + kk) * 512 + lane * 8];
#pragma unroll
        for (int t = 0; t < 4; ++t) {
          frag_ab bfr = *(const frag_ab*)(Wl + ((kk * 16 + (wv + 4 * t)) * 64 + lane) * 8);
          acc[t] = __builtin_amdgcn_mfma_f32_16x16x32_bf16(af, bfr, acc[t], 0, 0, 0);
        }
      }
      // all waves done READING row g before we overwrite it with Y
      __syncthreads();
#pragma unroll
      for (int p = 0; p < 2; ++p) {
        frag16 a0, a1;
#pragma unroll
        for (int r = 0; r < 4; ++r) {
          a0[r] = (short)f2bf(acc[p][r]);
          a1[r] = (short)f2bf(acc[p + 2][r]);
        }
        frag_cd d = (frag_cd){0.f, 0.f, 0.f, 0.f};
        d = __builtin_amdgcn_mfma_f32_16x16x16bf16_1k(a0, bd, d, 0, 0, 0);
        d = __builtin_amdgcn_mfma_f32_16x16x16bf16_1k(a1, boff, d, 0, 0, 0);
        int colbase = (p == 0) ? wv * 16 : 64 + wv * 16;
        frag16 sv;
#pragma unroll
        for (int r = 0; r < 4; ++r) {
          float v = d[r] + bias_s[colbase + q * 4 + r];
          ssum[p][r] += v;
          ssq[p][r] = fmaf(v, v, ssq[p][r]);
          sv[r] = (short)f2bf(v);
        }
        *(frag16*)&Hs[g * 2048 + (colbase / 8 + (q >> 1)) * 128 + m * 8 + (q & 1) * 4] = sv;
      }
      // no barrier after: group g+1 reads row g+1, disjoint from these writes
    }

    // ---- phase 3: BN stats -> stage k+1 (device-scope atomics @ LLC) ----
    float* so = stats + (size_t)(k + 1) * (NSLICE * 256);
#pragma unroll
    for (int p = 0; p < 2; ++p)
#pragma unroll
      for (int r = 0; r < 4; ++r) {
        float v1 = ssum[p][r], v2 = ssq[p][r];
        v1 += __shfl_xor(v1, 1); v2 += __shfl_xor(v2, 1);
        v1 += __shfl_xor(v1, 2); v2 += __shfl_xor(v2, 2);
        v1 += __shfl_xor(v1, 4); v2 += __shfl_xor(v2, 4);
        v1 += __shfl_xor(v1, 8); v2 += __shfl_xor(v2, 8);
        if (m == 0) {
          int c = ((p == 0) ? wv * 16 : 64 + wv * 16) + q * 4 + r;
          atomicAdd(&so[slice * 256 + c], v1);
          atomicAdd(&so[slice * 256 + 128 + c], v2);
        }
      }
  }

  // ---- out stage: BN + residual (from resbuf) + Fout=3 gconv ----
  grid.sync();
  {
    const float* st = stats + (size_t)8 * (NSLICE * 256);
    if (tid < 128) {
      float sum = 0.f, sq = 0.f;
#pragma unroll
      for (int s = 0; s < NSLICE; ++s) {
        sum += st[s * 256 + tid];
        sq += st[s * 256 + 128 + tid];
      }
      const float invN = 1.0f / (float)NROWS;
      float mu = sum * invN;
      float var = fmaxf(sq * invN - mu * mu, 0.f);
      float sc = g_res[7 * 128 + tid] * rsqrtf(var + 1e-5f);
      sc_s[tid] = sc;
      sh_s[tid] = beta_res[7 * 128 + tid] - mu * sc;
    }
    __syncthreads();

    for (int b4 = 0; b4 < 4; ++b4) {
      int bl = wv * 4 + b4;
      int b = b0 + bl;
      frag_cd acc = (frag_cd){0.f, 0.f, 0.f, 0.f};
#pragma unroll
      for (int kk = 0; kk < 4; ++kk) {
        int off = (bl * 4 + kk) * 512 + lane * 8;
        size_t base = (size_t)b0 * 2048 + off;
        frag_ab hv = *(const frag_ab*)&Hs[off];
        frag_ab rv = *(const frag_ab*)(resbuf + base);
        frag_ab bfrO = *(const frag_ab*)(Wopk_l + (kk * 64 + lane) * 8);
        const float* scp = &sc_s[kk * 32 + q * 8];
        const float* shp = &sh_s[kk * 32 + q * 8];
        frag_ab av;
#pragma unroll
        for (int e = 0; e < 8; ++e) {
          float a = fmaxf(0.f, fmaf(bf2f((unsigned short)hv[e]), scp[e], shp[e])) +
                    bf2f((unsigned short)rv[e]);
          av[e] = (short)f2bf(a);
        }
        acc = __builtin_amdgcn_mfma_f32_16x16x32_bf16(av, bfrO, acc, 0, 0, 0);
      }
      if (m < 6) {
#pragma unroll
        for (int r = 0; r < 4; ++r) ys[wv][m][q * 4 + r] = acc[r];
      }
      // same-wave LDS ops are in-order; no barrier needed (proven pattern)
      if (q < 3) {
        float v = bias_out[q] + attd_s[m] * ys[wv][q][m];
#pragma unroll
        for (int j = 0; j < 16; ++j) v = fmaf(att_s[m * 16 + j], ys[wv][3 + q][j], v);
        out[((size_t)b * 16 + m) * 3 + q] = v;
      }
    }
  }
}

// merged[b,j,c] = out_{1+c/3}[b,j,c%3]; out_i at d_out + i*393216
__global__ void pack_merged(const float* __restrict__ dout, float* __restrict__ merged) {
  int idx = blockIdx.x * 256 + threadIdx.x;
  if (idx >= BATCH * NJ * 12) return;
  int c = idx % 12;
  int bj = idx / 12;
  merged[idx] = dout[(size_t)(1 + c / 3) * 393216 + (size_t)bj * 3 + (c % 3)];
}

extern "C" void kernel_launch(void* const* d_in, const int* in_sizes, int n_in,
                              void* d_out, int out_size, void* d_ws, size_t ws_size,
                              hipStream_t stream) {
  (void)in_sizes; (void)n_in; (void)out_size; (void)ws_size;
  const float* W_in = (const float*)d_in[4];
  const float* b_in = (const float*)d_in[5];
  const float* e_in = (const float*)d_in[6];
  const float* g_in = (const float*)d_in[7];
  const float* beta_in = (const float*)d_in[8];
  const float* W_cat = (const float*)d_in[9];
  const float* b_cat = (const float*)d_in[10];
  const float* e_cat = (const float*)d_in[11];
  const float* g_cat = (const float*)d_in[12];
  const float* beta_cat = (const float*)d_in[13];
  const float* W_res = (const float*)d_in[14];
  const float* b_res = (const float*)d_in[15];
  const float* e_res = (const float*)d_in[16];
  const float* g_res = (const float*)d_in[17];
  const float* beta_res = (const float*)d_in[18];
  const float* W_out = (const float*)d_in[19];
  const float* b_out = (const float*)d_in[20];
  const float* e_out = (const float*)d_in[21];

  float* ws = (float*)d_ws;
  float* att_off = ws;                          // 3840 fl
  float* attd = att_off + 3840;                 // 240 fl (pad to 256)
  short* attB = (short*)(attd + 256);           // 15*512 shorts
  short* Wpk = attB + 15 * 512;                 // 8*64*512 = 262144 shorts
  short* Wopk = Wpk + 262144;                   // 5*2048 = 10240 shorts
  float* stats = (float*)(Wopk + 10240);        // 45 slots x 32 x 256 fl
  float* merged = stats + 45 * NSLICE * 256;    // B*16*12 fl
  u16* hbuf = (u16*)(merged + (size_t)BATCH * NJ * 12);  // 16777216 u16
  u16* Rg = hbuf + (size_t)BATCH * NJ * FHID;            // resbuf

  hipMemsetAsync(stats, 0, 45 * NSLICE * 256 * sizeof(float), stream);
  att_kernel<<<1, 256, 0, stream>>>(e_in, e_cat, e_res, e_out, att_off, attd);
  pack_attB<<<4, 256, 0, stream>>>(att_off, attd, attB);
  pack_w_kernel<<<128, 256, 0, stream>>>(W_res, Wpk);
  pack_wout<<<5, 256, 0, stream>>>(W_out, Wopk);

  float* dout = (float*)d_out;
  const int SSTRIDE = NSLICE * 256;

  // PRE-VALIDATE the fused path entirely on the host; never attempt a
  // cooperative launch that could fail (a failed launch during graph capture
  // can poison the capture).
  bool fused_ok = false;
  {
    int coop = 0, dev = 0;
    hipGetDevice(&dev);
    hipDeviceGetAttribute(&coop, hipDeviceAttributeCooperativeLaunch, dev);
    if (coop) {
      hipFuncAttributes fa;
      if (hipFuncGetAttributes(&fa, (const void*)stack_fused_kernel) == hipSuccess &&
          fa.localSizeBytes <= 64) {  // tolerate ABI-noise bytes; reject real spills
        int occ = 0;
        if (hipOccupancyMaxActiveBlocksPerMultiprocessor(
                &occ, (const void*)stack_fused_kernel, 256, 0) == hipSuccess &&
            occ >= 2) {
          fused_ok = true;  // 2 blocks/CU x 256 CUs >= grid 512
        }
      }
    }
  }

  auto run_stack_legacy = [&](int sb, const float* g0, const float* bt0, int out_layer,
                              const float* bo, int att_out_slot, float* optr) {
    for (int k = 0; k < 8; ++k) {
      const float* gg = (k == 0) ? g0 : g_res + (size_t)(k - 1) * FHID;
      const float* bb = (k == 0) ? bt0 : beta_res + (size_t)(k - 1) * FHID;
      int rm = (k == 0) ? 2 : ((k % 2 == 0) ? 3 : 0);
      gconv_mfma_kernel<<<BATCH / 8, 256, 0, stream>>>(
          hbuf, stats + (size_t)(sb + k) * SSTRIDE, gg, bb, Rg, rm,
          Wpk + (size_t)k * 32768, b_res + (size_t)k * FHID,
          attB + (size_t)(2 + k) * 512, hbuf,
          stats + (size_t)(sb + k + 1) * SSTRIDE);
    }
    gconv_out_kernel<<<BATCH / 8, 256, 0, stream>>>(
        hbuf, stats + (size_t)(sb + 8) * SSTRIDE, g_res + 7 * FHID,
        beta_res + 7 * FHID, Rg, Wopk + (size_t)out_layer * 2048, bo,
        att_off + (size_t)att_out_slot * 256, attd + (size_t)att_out_slot * 16,
        optr);
  };

  auto run_fused = [&](const float* g0p, const float* bt0p, int out_layer,
                       const float* bo, int slot, float* optr, float* st) -> bool {
    if (!fused_ok) return false;
    const u16* a0 = hbuf;
    float* a1 = st;
    const float* a2 = g0p;
    const float* a3 = bt0p;
    const float* a4 = g_res;
    const float* a5 = beta_res;
    const float* a6 = b_res;
    const short* a7 = Wpk;
    const short* a8 = attB;
    const short* a9 = Wopk + (size_t)out_layer * 2048;
    const float* a10 = bo;
    const float* a11 = att_off + (size_t)slot * 256;
    const float* a12 = attd + (size_t)slot * 16;
    u16* a13 = Rg;
    float* a14 = optr;
    void* args[15] = {&a0, &a1, &a2, &a3, &a4, &a5, &a6, &a7,
                      &a8, &a9, &a10, &a11, &a12, &a13, &a14};
    return hipLaunchCooperativeKernel((const void*)stack_fused_kernel, dim3(512),
                                      dim3(256), args, 0, stream) == hipSuccess;
  };

  for (int bi = 0; bi < 4; ++bi) {
    gconv_kernel<2><<<BATCH / 2, 256, 0, stream>>>(
        (const float*)d_in[bi], W_in, b_in, att_off, attd, hbuf,
        stats + (size_t)(bi * 9) * SSTRIDE);
    if (!run_fused(g_in, beta_in, bi, b_out + bi * 3, 10 + bi,
                   dout + (size_t)(1 + bi) * 393216,
                   stats + (size_t)(bi * 9) * SSTRIDE))
      run_stack_legacy(bi * 9, g_in, beta_in, bi, b_out + bi * 3, 10 + bi,
                       dout + (size_t)(1 + bi) * 393216);
  }

  pack_merged<<<(BATCH * NJ * 12 + 255) / 256, 256, 0, stream>>>(dout, merged);
  gconv_kernel<12><<<BATCH / 2, 256, 0, stream>>>(
      merged, W_cat, b_cat, att_off + 256, attd + 16, hbuf,
      stats + (size_t)36 * SSTRIDE);
  if (!run_fused(g_cat, beta_cat, 4, b_out + 12, 14, dout,
                 stats + (size_t)36 * SSTRIDE))
    run_stack_legacy(36, g_cat, beta_cat, 4, b_out + 12, 14, dout);
}